// Round 5
// baseline (1412.406 us; speedup 1.0000x reference)
//
#include <hip/hip_runtime.h>

#define T_LEN   131072
#define IN_DIM  256
#define HD      64
#define PD      32
#define NLAY    4
#define CHUNK   128
#define NBLK    (T_LEN / CHUNK)   // 1024

// ---------------------------------------------------------------- K0: setup
__global__ __launch_bounds__(512) void ssm_k0_setup(
    const float* __restrict__ Lre, const float* __restrict__ Lim,
    const float* __restrict__ logstep,
    const float* __restrict__ Bre, const float* __restrict__ Bim,
    const float* __restrict__ Cre, const float* __restrict__ Cim,
    const float* __restrict__ w1, const float* __restrict__ w2,
    const float* __restrict__ enc_w, const int* __restrict__ gptr,
    float* __restrict__ Lbar, float* __restrict__ Ldt,
    float* __restrict__ Bbar_t, float* __restrict__ Ct,
    float* __restrict__ w1t, float* __restrict__ w2t,
    float* __restrict__ wenc, float* __restrict__ stats)
{
    __shared__ float fact[NLAY * PD * 2];
    int tid = threadIdx.x;
    if (tid < NLAY * PD) {
        int l = tid >> 5, p = tid & 31;
        float dt = expf(logstep[l * PD + p]);
        float lr = Lre[l * PD + p], li = Lim[l * PD + p];
        float ldr = lr * dt, ldi = li * dt;
        Ldt[tid * 2] = ldr; Ldt[tid * 2 + 1] = ldi;
        float e = expf(ldr);
        float sn, cs; sincosf(ldi, &sn, &cs);
        float lbr = e * cs, lbi = e * sn;
        Lbar[tid * 2] = lbr; Lbar[tid * 2 + 1] = lbi;
        float den = lr * lr + li * li;
        float nr = lbr - 1.0f, ni = lbi;
        fact[tid * 2]     = (nr * lr + ni * li) / den;
        fact[tid * 2 + 1] = (ni * lr - nr * li) / den;
    }
    if (tid < NLAY * 128) stats[tid] = 0.0f;
    __syncthreads();
    // Bbar_t[l][c][2p] ; Ct planes [l][p][re:0..63 | im:64..127]
    for (int idx = tid; idx < NLAY * PD * HD; idx += 512) {
        int lp = idx >> 6; int c = idx & 63;
        int l = lp >> 5, p = lp & 31;
        float fr = fact[lp * 2], fi = fact[lp * 2 + 1];
        float br = Bre[idx], bi = Bim[idx];                    // B is [l][p][h]
        Bbar_t[((size_t)(l * HD + c)) * HD + 2 * p]     = fr * br - fi * bi;
        Bbar_t[((size_t)(l * HD + c)) * HD + 2 * p + 1] = fr * bi + fi * br;
        Ct[((size_t)(l * PD + p)) * 128 + c]      = Cre[(l * HD + c) * PD + p];
        Ct[((size_t)(l * PD + p)) * 128 + 64 + c] = Cim[(l * HD + c) * PD + p];
    }
    for (int idx = tid; idx < NLAY * HD * HD; idx += 512) {
        int l = idx >> 12; int k = (idx >> 6) & 63; int c = idx & 63;
        w1t[idx] = w1[(l * HD + c) * HD + k];
        w2t[idx] = w2[(l * HD + c) * HD + k];
    }
    int g = gptr[0];
    for (int idx = tid; idx < IN_DIM * HD; idx += 512) {
        int k = idx >> 6, ch = idx & 63;
        wenc[idx] = (ch < 56) ? enc_w[((size_t)(g * 56 + ch)) * IN_DIM + k] : 0.0f;
    }
}

// ---------------------------------------------------------------- K1: encoder
// 2048 blocks x 256 threads (4 waves). wave = cg, lane = row (64 rows/block).
// x double-buffered in LDS (reg-staged); weights via VMEM broadcast (vmcnt),
// NOT s_load: SGPR cap prevented prefetch, and ds+smem share lgkmcnt.
__global__ __launch_bounds__(256, 4) void ssm_k1_encoder(
    const float* __restrict__ x, const int* __restrict__ gptr,
    const float* __restrict__ wenc, const float* __restrict__ enc_b,
    const float* __restrict__ ctx_emb,
    float* __restrict__ h, float* __restrict__ stats)
{
    __shared__ float xl[2][64 * 66];
    __shared__ float sp1[64], sp2[64];
    int tid = threadIdx.x;
    int lane = tid & 63, wid = tid >> 6;
    int cg = wid & 3;              // plain (divergent to compiler) -> VMEM weights
    int row = lane;
    int g = gptr[0];
    size_t r0 = (size_t)blockIdx.x * 64;

    float acc[16];
#pragma unroll
    for (int i = 0; i < 16; ++i) {
        int ch = cg * 16 + i;
        acc[i] = (ch < 56) ? enc_b[g * 56 + ch] : 0.0f;
    }

    float4 stg[4];
    // prologue: stage kt=0
#pragma unroll
    for (int it = 0; it < 4; ++it) {
        int idx = it * 256 + tid;
        int rr = idx >> 4, c4 = idx & 15;
        stg[it] = *(const float4*)&x[(r0 + rr) * IN_DIM + c4 * 4];
    }
#pragma unroll
    for (int it = 0; it < 4; ++it) {
        int idx = it * 256 + tid;
        int rr = idx >> 4, c4 = idx & 15;
        *(float2*)&xl[0][rr * 66 + c4 * 4]     = make_float2(stg[it].x, stg[it].y);
        *(float2*)&xl[0][rr * 66 + c4 * 4 + 2] = make_float2(stg[it].z, stg[it].w);
    }
    __syncthreads();

    for (int kt = 0; kt < 4; ++kt) {
        if (kt < 3) {   // issue next-tile loads; latency hides under compute
#pragma unroll
            for (int it = 0; it < 4; ++it) {
                int idx = it * 256 + tid;
                int rr = idx >> 4, c4 = idx & 15;
                stg[it] = *(const float4*)&x[(r0 + rr) * IN_DIM + (kt + 1) * 64 + c4 * 4];
            }
        }
        const float* xbuf = xl[kt & 1];
        for (int k2 = 0; k2 < 32; ++k2) {
            float2 xv = *(const float2*)&xbuf[row * 66 + 2 * k2];
            const float* wp = &wenc[(size_t)(kt * 64 + 2 * k2) * 64 + cg * 16];
            float4 a0 = *(const float4*)&wp[0],  a1 = *(const float4*)&wp[4];
            float4 a2 = *(const float4*)&wp[8],  a3 = *(const float4*)&wp[12];
            float4 b0 = *(const float4*)&wp[64], b1v = *(const float4*)&wp[68];
            float4 b2v = *(const float4*)&wp[72], b3 = *(const float4*)&wp[76];
            acc[0]  += xv.x * a0.x + xv.y * b0.x;   acc[1]  += xv.x * a0.y + xv.y * b0.y;
            acc[2]  += xv.x * a0.z + xv.y * b0.z;   acc[3]  += xv.x * a0.w + xv.y * b0.w;
            acc[4]  += xv.x * a1.x + xv.y * b1v.x;  acc[5]  += xv.x * a1.y + xv.y * b1v.y;
            acc[6]  += xv.x * a1.z + xv.y * b1v.z;  acc[7]  += xv.x * a1.w + xv.y * b1v.w;
            acc[8]  += xv.x * a2.x + xv.y * b2v.x;  acc[9]  += xv.x * a2.y + xv.y * b2v.y;
            acc[10] += xv.x * a2.z + xv.y * b2v.z;  acc[11] += xv.x * a2.w + xv.y * b2v.w;
            acc[12] += xv.x * a3.x + xv.y * b3.x;   acc[13] += xv.x * a3.y + xv.y * b3.y;
            acc[14] += xv.x * a3.z + xv.y * b3.z;   acc[15] += xv.x * a3.w + xv.y * b3.w;
        }
        if (kt < 3) {   // write next tile (other buffer: prev readers are past it)
#pragma unroll
            for (int it = 0; it < 4; ++it) {
                int idx = it * 256 + tid;
                int rr = idx >> 4, c4 = idx & 15;
                *(float2*)&xl[(kt + 1) & 1][rr * 66 + c4 * 4]     = make_float2(stg[it].x, stg[it].y);
                *(float2*)&xl[(kt + 1) & 1][rr * 66 + c4 * 4 + 2] = make_float2(stg[it].z, stg[it].w);
            }
            __syncthreads();
        }
    }
    // ctx channels (56..63) override
    if (cg == 3) {
#pragma unroll
        for (int i = 8; i < 16; ++i) acc[i] = ctx_emb[g * 8 + (i - 8)];
    }
#pragma unroll
    for (int j4 = 0; j4 < 4; ++j4)
        *(float4*)&h[(r0 + row) * HD + cg * 16 + j4 * 4] =
            make_float4(acc[j4 * 4], acc[j4 * 4 + 1], acc[j4 * 4 + 2], acc[j4 * 4 + 3]);
    // layer-0 stats: each wave owns its 16 channels; lanes are 64 distinct rows
#pragma unroll
    for (int i = 0; i < 16; ++i) {
        float v1 = acc[i], v2 = acc[i] * acc[i];
#pragma unroll
        for (int m = 1; m < 64; m <<= 1) { v1 += __shfl_xor(v1, m, 64); v2 += __shfl_xor(v2, m, 64); }
        if (lane == 0) { sp1[wid * 16 + i] = v1; sp2[wid * 16 + i] = v2; }
    }
    __syncthreads();
    if (tid < 64) {
        atomicAdd(&stats[tid],      sp1[tid]);
        atomicAdd(&stats[64 + tid], sp2[tid]);
    }
}

// ---------------------------------------------------------------- K2: hn -> Bu -> local scan
// 512 threads; weights via VMEM broadcast (plain cg).
__global__ __launch_bounds__(512, 4) void ssm_k2_bu_scan(
    const float* __restrict__ h, const float* __restrict__ stats,
    const float* __restrict__ nscale, const float* __restrict__ nbias,
    const float* __restrict__ Bbar_t, const float* __restrict__ Lbar,
    float* __restrict__ xs, float* __restrict__ carry, int l)
{
    __shared__ float buf[128 * 66];
    __shared__ float sa[HD], sb[HD];
    int tid = threadIdx.x;
    int lane = tid & 63, wid = tid >> 6;
    int cg = wid & 3;
    int row = (wid >> 2) * 64 + lane;
    size_t r0 = (size_t)blockIdx.x * CHUNK;

    if (tid < HD) {
        float s1 = stats[l * 128 + tid], s2 = stats[l * 128 + 64 + tid];
        float mu = s1 * (1.0f / T_LEN);
        float var = fmaxf(s2 * (1.0f / T_LEN) - mu * mu, 0.0f);
        float sc = nscale[l * HD + tid] * rsqrtf(var + 1e-5f);
        sa[tid] = sc;
        sb[tid] = nbias[l * HD + tid] - mu * sc;
    }
    __syncthreads();

#pragma unroll
    for (int j4 = 0; j4 < 4; ++j4) {
        float4 hv = *(const float4*)&h[(r0 + row) * HD + cg * 16 + j4 * 4];
        int c = cg * 16 + j4 * 4;
        float2 a = make_float2(hv.x * sa[c]     + sb[c],     hv.y * sa[c + 1] + sb[c + 1]);
        float2 b = make_float2(hv.z * sa[c + 2] + sb[c + 2], hv.w * sa[c + 3] + sb[c + 3]);
        *(float2*)&buf[row * 66 + c]     = a;
        *(float2*)&buf[row * 66 + c + 2] = b;
    }
    __syncthreads();

    float bacc[16];
#pragma unroll
    for (int j = 0; j < 16; ++j) bacc[j] = 0.0f;
    for (int k2 = 0; k2 < 32; ++k2) {
        float2 hk = *(float2*)&buf[row * 66 + 2 * k2];
        const float* b0 = &Bbar_t[(size_t)l * 4096 + (2 * k2) * 64 + cg * 16];
        const float* b1p = b0 + 64;
        float4 a0 = *(const float4*)&b0[0],  a1 = *(const float4*)&b0[4];
        float4 a2 = *(const float4*)&b0[8],  a3 = *(const float4*)&b0[12];
        float4 c0 = *(const float4*)&b1p[0], c1 = *(const float4*)&b1p[4];
        float4 c2 = *(const float4*)&b1p[8], c3 = *(const float4*)&b1p[12];
        bacc[0]  += hk.x * a0.x + hk.y * c0.x;  bacc[1]  += hk.x * a0.y + hk.y * c0.y;
        bacc[2]  += hk.x * a0.z + hk.y * c0.z;  bacc[3]  += hk.x * a0.w + hk.y * c0.w;
        bacc[4]  += hk.x * a1.x + hk.y * c1.x;  bacc[5]  += hk.x * a1.y + hk.y * c1.y;
        bacc[6]  += hk.x * a1.z + hk.y * c1.z;  bacc[7]  += hk.x * a1.w + hk.y * c1.w;
        bacc[8]  += hk.x * a2.x + hk.y * c2.x;  bacc[9]  += hk.x * a2.y + hk.y * c2.y;
        bacc[10] += hk.x * a2.z + hk.y * c2.z;  bacc[11] += hk.x * a2.w + hk.y * c2.w;
        bacc[12] += hk.x * a3.x + hk.y * c3.x;  bacc[13] += hk.x * a3.y + hk.y * c3.y;
        bacc[14] += hk.x * a3.z + hk.y * c3.z;  bacc[15] += hk.x * a3.w + hk.y * c3.w;
    }
    __syncthreads();
#pragma unroll
    for (int j2 = 0; j2 < 8; ++j2)
        *(float2*)&buf[row * 66 + cg * 16 + 2 * j2] =
            make_float2(bacc[2 * j2], bacc[2 * j2 + 1]);
    __syncthreads();

    if (tid < 64) {
        int p = lane >> 1;
        float Lr = Lbar[(l * PD + p) * 2];
        float Lj = Lbar[(l * PD + p) * 2 + 1];
        float csn = (lane & 1) ? Lj : -Lj;
        float xv = 0.0f;
        for (int t = 0; t < CHUNK; ++t) {
            float b = buf[t * 66 + lane];
            float xo = __shfl_xor(xv, 1, 64);
            xv = Lr * xv + csn * xo + b;
            buf[t * 66 + lane] = xv;
        }
        carry[(size_t)blockIdx.x * 64 + lane] = xv;
    }
    __syncthreads();
#pragma unroll
    for (int j4 = 0; j4 < 4; ++j4) {
        float2 a = *(float2*)&buf[row * 66 + cg * 16 + 4 * j4];
        float2 b = *(float2*)&buf[row * 66 + cg * 16 + 4 * j4 + 2];
        *(float4*)&xs[(r0 + row) * HD + cg * 16 + 4 * j4] = make_float4(a.x, a.y, b.x, b.y);
    }
}

// ---------------------------------------------------------------- K3: cross-chunk carry scan (unchanged)
__global__ __launch_bounds__(64) void ssm_k3_carry(
    const float* __restrict__ carry, const float* __restrict__ Ldt,
    float* __restrict__ pc, int l)
{
    int p = blockIdx.x;
    int lane = threadIdx.x;
    float ldr = Ldt[(l * PD + p) * 2], ldi = Ldt[(l * PD + p) * 2 + 1];
    float er = __expf(ldr * (float)CHUNK);
    float an = ldi * (float)CHUNK;
    float lcr = er * __cosf(an), lci = er * __sinf(an);   // L^CHUNK
    float cr[16], ci[16];
#pragma unroll
    for (int j = 0; j < 16; ++j) {
        cr[j] = carry[(size_t)(lane * 16 + j) * 64 + 2 * p];
        ci[j] = carry[(size_t)(lane * 16 + j) * 64 + 2 * p + 1];
    }
    float ur = 0.0f, ui = 0.0f;
#pragma unroll
    for (int j = 0; j < 16; ++j) {
        float nr = lcr * ur - lci * ui + cr[j];
        float ni = lcr * ui + lci * ur + ci[j];
        ur = nr; ui = ni;
    }
    float mr = lcr, mi = lci;
#pragma unroll
    for (int s = 0; s < 4; ++s) { float t = mr * mr - mi * mi; mi = 2.0f * mr * mi; mr = t; }
#pragma unroll
    for (int d = 1; d < 64; d <<= 1) {
        float tr = __shfl_up(ur, d, 64);
        float ti = __shfl_up(ui, d, 64);
        if (lane >= d) { ur = mr * tr - mi * ti + ur; ui = mr * ti + mi * tr + ui; }
        float t = mr * mr - mi * mi; mi = 2.0f * mr * mi; mr = t;
    }
    float pr = __shfl_up(ur, 1, 64), pi = __shfl_up(ui, 1, 64);
    float xr = (lane == 0) ? 0.0f : pr;
    float xi = (lane == 0) ? 0.0f : pi;
#pragma unroll
    for (int j = 0; j < 16; ++j) {
        pc[(size_t)(lane * 16 + j) * 64 + 2 * p]     = xr;
        pc[(size_t)(lane * 16 + j) * 64 + 2 * p + 1] = xi;
        float nr = lcr * xr - lci * xi + cr[j];
        float ni = lcr * xi + lci * xr + ci[j];
        xr = nr; xi = ni;
    }
}

// ---------------------------------------------------------------- K4: fixup + C-proj + gelu + GLU + residual (+stats / decoder)
// 2048 blocks x 256 threads (4 waves); wave = cg, lane = row (64 rows/block).
// Weights via VMEM broadcast.
template <bool LAST>
__global__ __launch_bounds__(256, 4) void ssm_k4_out(
    const float* __restrict__ h, const float* __restrict__ xs,
    const float* __restrict__ pc, const float* __restrict__ stats,
    const float* __restrict__ nscale, const float* __restrict__ nbias,
    const float* __restrict__ Ldt, const float* __restrict__ Ct,
    const float* __restrict__ Dv,
    const float* __restrict__ w1t, const float* __restrict__ b1,
    const float* __restrict__ w2t, const float* __restrict__ b2,
    float* __restrict__ hout, float* __restrict__ stats_next,
    const float* __restrict__ dec_w, const float* __restrict__ dec_b,
    float* __restrict__ outp, int l)
{
    __shared__ float buf[64 * 66];
    __shared__ float sa[HD], sb[HD];
    __shared__ float sp1[64], sp2[64];
    int tid = threadIdx.x;
    int lane = tid & 63, wid = tid >> 6;
    int cg = wid & 3;
    int row = lane;                                   // local row in 64-row block
    size_t r0 = (size_t)blockIdx.x * 64;
    int chunk = blockIdx.x >> 1;                      // 128-row scan chunk
    int tloc = ((blockIdx.x & 1) << 6) + lane;        // row index within chunk

    if (tid < HD) {
        float s1 = stats[l * 128 + tid], s2 = stats[l * 128 + 64 + tid];
        float mu = s1 * (1.0f / T_LEN);
        float var = fmaxf(s2 * (1.0f / T_LEN) - mu * mu, 0.0f);
        float sc = nscale[l * HD + tid] * rsqrtf(var + 1e-5f);
        sa[tid] = sc;
        sb[tid] = nbias[l * HD + tid] - mu * sc;
    }

    // xs slice + carry fixup
    float xf[16];
#pragma unroll
    for (int j4 = 0; j4 < 4; ++j4)
        *(float4*)&xf[j4 * 4] = *(const float4*)&xs[(r0 + row) * HD + cg * 16 + j4 * 4];
    {
        const float* ldp = &Ldt[(l * PD + cg * 8) * 2];
        const float* pcp = &pc[(size_t)chunk * 64 + cg * 16];
        float tt = (float)(tloc + 1);
#pragma unroll
        for (int pp = 0; pp < 8; ++pp) {
            float e = __expf(ldp[2 * pp] * tt);
            float an = ldp[2 * pp + 1] * tt;
            float prr = e * __cosf(an), pri = e * __sinf(an);
            float pr_ = pcp[2 * pp], pi_ = pcp[2 * pp + 1];
            xf[2 * pp]     += prr * pr_ - pri * pi_;
            xf[2 * pp + 1] += prr * pi_ + pri * pr_;
        }
    }
#pragma unroll
    for (int j2 = 0; j2 < 8; ++j2)
        *(float2*)&buf[row * 66 + cg * 16 + 2 * j2] =
            make_float2(xf[2 * j2], xf[2 * j2 + 1]);
    __syncthreads();

    // C projection
    float y[16];
#pragma unroll
    for (int i = 0; i < 16; ++i) y[i] = 0.0f;
    for (int p = 0; p < 32; ++p) {
        float2 xv = *(float2*)&buf[row * 66 + 2 * p];
        const float* cp = &Ct[(size_t)l * 4096 + p * 128 + cg * 16];
        float4 r0v = *(const float4*)&cp[0],  r1v = *(const float4*)&cp[4];
        float4 r2v = *(const float4*)&cp[8],  r3v = *(const float4*)&cp[12];
        float4 i0v = *(const float4*)&cp[64], i1v = *(const float4*)&cp[68];
        float4 i2v = *(const float4*)&cp[72], i3v = *(const float4*)&cp[76];
        y[0]  += xv.x * r0v.x - xv.y * i0v.x;  y[1]  += xv.x * r0v.y - xv.y * i0v.y;
        y[2]  += xv.x * r0v.z - xv.y * i0v.z;  y[3]  += xv.x * r0v.w - xv.y * i0v.w;
        y[4]  += xv.x * r1v.x - xv.y * i1v.x;  y[5]  += xv.x * r1v.y - xv.y * i1v.y;
        y[6]  += xv.x * r1v.z - xv.y * i1v.z;  y[7]  += xv.x * r1v.w - xv.y * i1v.w;
        y[8]  += xv.x * r2v.x - xv.y * i2v.x;  y[9]  += xv.x * r2v.y - xv.y * i2v.y;
        y[10] += xv.x * r2v.z - xv.y * i2v.z;  y[11] += xv.x * r2v.w - xv.y * i2v.w;
        y[12] += xv.x * r3v.x - xv.y * i3v.x;  y[13] += xv.x * r3v.y - xv.y * i3v.y;
        y[14] += xv.x * r3v.z - xv.y * i3v.z;  y[15] += xv.x * r3v.w - xv.y * i3v.w;
    }

    // h row, gelu(2y + hn*D)
    float hrow[16], g[16];
#pragma unroll
    for (int j4 = 0; j4 < 4; ++j4)
        *(float4*)&hrow[j4 * 4] = *(const float4*)&h[(r0 + row) * HD + cg * 16 + j4 * 4];
    {
        const float* dvp = &Dv[l * HD + cg * 16];
#pragma unroll
        for (int i = 0; i < 16; ++i) {
            int c = cg * 16 + i;
            float hnv = hrow[i] * sa[c] + sb[c];
            float t = 2.0f * y[i] + hnv * dvp[i];
            float u2 = 1.5957691216057308f * (t + 0.044715f * t * t * t);
            g[i] = t / (1.0f + __expf(-u2));
        }
    }
    __syncthreads();
#pragma unroll
    for (int j2 = 0; j2 < 8; ++j2)
        *(float2*)&buf[row * 66 + cg * 16 + 2 * j2] =
            make_float2(g[2 * j2], g[2 * j2 + 1]);
    __syncthreads();

    // GLU
    float uacc[16], sacc[16];
    {
        const float* b1p = &b1[l * HD + cg * 16];
        const float* b2p = &b2[l * HD + cg * 16];
#pragma unroll
        for (int j4 = 0; j4 < 4; ++j4) {
            *(float4*)&uacc[j4 * 4] = *(const float4*)&b1p[j4 * 4];
            *(float4*)&sacc[j4 * 4] = *(const float4*)&b2p[j4 * 4];
        }
    }
    for (int k2 = 0; k2 < 32; ++k2) {
        float2 gk = *(float2*)&buf[row * 66 + 2 * k2];
        const float* p1 = &w1t[(size_t)l * 4096 + (2 * k2) * 64 + cg * 16];
        const float* p2 = &w2t[(size_t)l * 4096 + (2 * k2) * 64 + cg * 16];
        float4 a00 = *(const float4*)&p1[0],  a01 = *(const float4*)&p1[4];
        float4 a02 = *(const float4*)&p1[8],  a03 = *(const float4*)&p1[12];
        float4 a10 = *(const float4*)&p1[64], a11 = *(const float4*)&p1[68];
        float4 a12 = *(const float4*)&p1[72], a13 = *(const float4*)&p1[76];
        float4 c00 = *(const float4*)&p2[0],  c01 = *(const float4*)&p2[4];
        float4 c02 = *(const float4*)&p2[8],  c03 = *(const float4*)&p2[12];
        float4 c10 = *(const float4*)&p2[64], c11 = *(const float4*)&p2[68];
        float4 c12 = *(const float4*)&p2[72], c13 = *(const float4*)&p2[76];
        uacc[0]  += gk.x * a00.x + gk.y * a10.x;  uacc[1]  += gk.x * a00.y + gk.y * a10.y;
        uacc[2]  += gk.x * a00.z + gk.y * a10.z;  uacc[3]  += gk.x * a00.w + gk.y * a10.w;
        uacc[4]  += gk.x * a01.x + gk.y * a11.x;  uacc[5]  += gk.x * a01.y + gk.y * a11.y;
        uacc[6]  += gk.x * a01.z + gk.y * a11.z;  uacc[7]  += gk.x * a01.w + gk.y * a11.w;
        uacc[8]  += gk.x * a02.x + gk.y * a12.x;  uacc[9]  += gk.x * a02.y + gk.y * a12.y;
        uacc[10] += gk.x * a02.z + gk.y * a12.z;  uacc[11] += gk.x * a02.w + gk.y * a12.w;
        uacc[12] += gk.x * a03.x + gk.y * a13.x;  uacc[13] += gk.x * a03.y + gk.y * a13.y;
        uacc[14] += gk.x * a03.z + gk.y * a13.z;  uacc[15] += gk.x * a03.w + gk.y * a13.w;
        sacc[0]  += gk.x * c00.x + gk.y * c10.x;  sacc[1]  += gk.x * c00.y + gk.y * c10.y;
        sacc[2]  += gk.x * c00.z + gk.y * c10.z;  sacc[3]  += gk.x * c00.w + gk.y * c10.w;
        sacc[4]  += gk.x * c01.x + gk.y * c11.x;  sacc[5]  += gk.x * c01.y + gk.y * c11.y;
        sacc[6]  += gk.x * c01.z + gk.y * c11.z;  sacc[7]  += gk.x * c01.w + gk.y * c11.w;
        sacc[8]  += gk.x * c02.x + gk.y * c12.x;  sacc[9]  += gk.x * c02.y + gk.y * c12.y;
        sacc[10] += gk.x * c02.z + gk.y * c12.z;  sacc[11] += gk.x * c02.w + gk.y * c12.w;
        sacc[12] += gk.x * c03.x + gk.y * c13.x;  sacc[13] += gk.x * c03.y + gk.y * c13.y;
        sacc[14] += gk.x * c03.z + gk.y * c13.z;  sacc[15] += gk.x * c03.w + gk.y * c13.w;
    }

    if (LAST) {
        const float* dwp0 = &dec_w[cg * 16];
        const float* dwp1 = &dec_w[64 + cg * 16];
        float o0 = 0.0f, o1 = 0.0f;
#pragma unroll
        for (int i = 0; i < 16; ++i) {
            float sg = 1.0f / (1.0f + __expf(-sacc[i]));
            float ho = hrow[i] + uacc[i] * sg;
            o0 += ho * dwp0[i];
            o1 += ho * dwp1[i];
        }
        __syncthreads();   // all g reads done before reusing buf for partials
        buf[row * 8 + cg * 2]     = o0;
        buf[row * 8 + cg * 2 + 1] = o1;
        __syncthreads();
        if (tid < 64) {
            float a0 = buf[tid * 8] + buf[tid * 8 + 2] + buf[tid * 8 + 4] + buf[tid * 8 + 6];
            float a1 = buf[tid * 8 + 1] + buf[tid * 8 + 3] + buf[tid * 8 + 5] + buf[tid * 8 + 7];
            *(float2*)&outp[(r0 + tid) * 2] = make_float2(a0 + dec_b[0], a1 + dec_b[1]);
        }
    } else {
        float ho[16];
#pragma unroll
        for (int i = 0; i < 16; ++i) {
            float sg = 1.0f / (1.0f + __expf(-sacc[i]));
            ho[i] = hrow[i] + uacc[i] * sg;
        }
#pragma unroll
        for (int j4 = 0; j4 < 4; ++j4)
            *(float4*)&hout[(r0 + row) * HD + cg * 16 + j4 * 4] =
                make_float4(ho[j4 * 4], ho[j4 * 4 + 1], ho[j4 * 4 + 2], ho[j4 * 4 + 3]);
#pragma unroll
        for (int i = 0; i < 16; ++i) {
            float v1 = ho[i], v2 = ho[i] * ho[i];
#pragma unroll
            for (int m = 1; m < 64; m <<= 1) { v1 += __shfl_xor(v1, m, 64); v2 += __shfl_xor(v2, m, 64); }
            if (lane == 0) { sp1[wid * 16 + i] = v1; sp2[wid * 16 + i] = v2; }
        }
        __syncthreads();
        if (tid < 64) {
            atomicAdd(&stats_next[tid],      sp1[tid]);
            atomicAdd(&stats_next[64 + tid], sp2[tid]);
        }
    }
}

// ---------------------------------------------------------------- launch
extern "C" void kernel_launch(void* const* d_in, const int* in_sizes, int n_in,
                              void* d_out, int out_size, void* d_ws, size_t ws_size,
                              hipStream_t stream)
{
    (void)in_sizes; (void)n_in; (void)out_size; (void)ws_size;
    const float* x     = (const float*)d_in[0];
    const int*   gidx  = (const int*)d_in[1];
    const float* enc_w = (const float*)d_in[2];
    const float* enc_b = (const float*)d_in[3];
    const float* ctx   = (const float*)d_in[4];
    const float* Lre   = (const float*)d_in[5];
    const float* Lim   = (const float*)d_in[6];
    const float* Bre   = (const float*)d_in[7];
    const float* Bim   = (const float*)d_in[8];
    const float* Cre   = (const float*)d_in[9];
    const float* Cim   = (const float*)d_in[10];
    const float* Dv    = (const float*)d_in[11];
    const float* lstep = (const float*)d_in[12];
    const float* nsc   = (const float*)d_in[13];
    const float* nbi   = (const float*)d_in[14];
    const float* w1    = (const float*)d_in[15];
    const float* b1    = (const float*)d_in[16];
    const float* w2    = (const float*)d_in[17];
    const float* b2    = (const float*)d_in[18];
    const float* dw    = (const float*)d_in[19];
    const float* db    = (const float*)d_in[20];
    float* out = (float*)d_out;

    float* ws = (float*)d_ws;
    float* h      = ws;  ws += (size_t)T_LEN * HD;
    float* xs     = ws;  ws += (size_t)T_LEN * HD;
    float* carry  = ws;  ws += (size_t)NBLK * HD;
    float* pc     = ws;  ws += (size_t)NBLK * HD;
    float* stats  = ws;  ws += NLAY * 128;
    float* Lbar   = ws;  ws += NLAY * PD * 2;
    float* Ldt    = ws;  ws += NLAY * PD * 2;
    float* Bbar_t = ws;  ws += NLAY * HD * HD;
    float* Ct     = ws;  ws += NLAY * PD * 128;
    float* w1t    = ws;  ws += NLAY * HD * HD;
    float* w2t    = ws;  ws += NLAY * HD * HD;
    float* wenc   = ws;  ws += IN_DIM * HD;

    ssm_k0_setup<<<1, 512, 0, stream>>>(Lre, Lim, lstep, Bre, Bim, Cre, Cim, w1, w2,
                                        enc_w, gidx, Lbar, Ldt, Bbar_t, Ct, w1t, w2t,
                                        wenc, stats);
    ssm_k1_encoder<<<2048, 256, 0, stream>>>(x, gidx, wenc, enc_b, ctx, h, stats);
    for (int l = 0; l < NLAY; ++l) {
        ssm_k2_bu_scan<<<NBLK, 512, 0, stream>>>(h, stats, nsc, nbi, Bbar_t, Lbar, xs, carry, l);
        ssm_k3_carry<<<PD, 64, 0, stream>>>(carry, Ldt, pc, l);
        if (l < NLAY - 1) {
            ssm_k4_out<false><<<2048, 256, 0, stream>>>(
                h, xs, pc, stats, nsc, nbi, Ldt, Ct, Dv, w1t, b1, w2t, b2,
                h, stats + (l + 1) * 128, dw, db, out, l);
        } else {
            ssm_k4_out<true><<<2048, 256, 0, stream>>>(
                h, xs, pc, stats, nsc, nbi, Ldt, Ct, Dv, w1t, b1, w2t, b2,
                h, stats, dw, db, out, l);
        }
    }
}

// Round 6
// 582.032 us; speedup vs baseline: 2.4267x; 2.4267x over previous
//
#include <hip/hip_runtime.h>

#define T_LEN   131072
#define IN_DIM  256
#define HD      64
#define PD      32
#define NLAY    4
#define CHUNK   128
#define NBLK    (T_LEN / CHUNK)   // 1024
#define BSTR    68                // LDS row stride (floats): 272B, 16B-aligned

__device__ __forceinline__ float compsel(float4 v, int kk) {
    return kk == 0 ? v.x : kk == 1 ? v.y : kk == 2 ? v.z : v.w;
}

// ---------------------------------------------------------------- K0: setup
__global__ __launch_bounds__(512) void ssm_k0_setup(
    const float* __restrict__ Lre, const float* __restrict__ Lim,
    const float* __restrict__ logstep,
    const float* __restrict__ Bre, const float* __restrict__ Bim,
    const float* __restrict__ Cre, const float* __restrict__ Cim,
    const float* __restrict__ w1, const float* __restrict__ w2,
    const float* __restrict__ enc_w, const int* __restrict__ gptr,
    float* __restrict__ Lbar, float* __restrict__ Ldt,
    float* __restrict__ Bbar_t, float* __restrict__ Ct,
    float* __restrict__ w1t, float* __restrict__ w2t,
    float* __restrict__ wenc, float* __restrict__ stats)
{
    __shared__ float fact[NLAY * PD * 2];
    int tid = threadIdx.x;
    if (tid < NLAY * PD) {
        int l = tid >> 5, p = tid & 31;
        float dt = expf(logstep[l * PD + p]);
        float lr = Lre[l * PD + p], li = Lim[l * PD + p];
        float ldr = lr * dt, ldi = li * dt;
        Ldt[tid * 2] = ldr; Ldt[tid * 2 + 1] = ldi;
        float e = expf(ldr);
        float sn, cs; sincosf(ldi, &sn, &cs);
        float lbr = e * cs, lbi = e * sn;
        Lbar[tid * 2] = lbr; Lbar[tid * 2 + 1] = lbi;
        float den = lr * lr + li * li;
        float nr = lbr - 1.0f, ni = lbi;
        fact[tid * 2]     = (nr * lr + ni * li) / den;
        fact[tid * 2 + 1] = (ni * lr - nr * li) / den;
    }
    if (tid < NLAY * 128) stats[tid] = 0.0f;
    __syncthreads();
    // Bbar_t[l][k=c][2p] ; Ct planes [l][p][re:0..63 | im:64..127]
    for (int idx = tid; idx < NLAY * PD * HD; idx += 512) {
        int lp = idx >> 6; int c = idx & 63;
        int l = lp >> 5, p = lp & 31;
        float fr = fact[lp * 2], fi = fact[lp * 2 + 1];
        float br = Bre[idx], bi = Bim[idx];                    // B is [l][p][h]
        Bbar_t[((size_t)(l * HD + c)) * HD + 2 * p]     = fr * br - fi * bi;
        Bbar_t[((size_t)(l * HD + c)) * HD + 2 * p + 1] = fr * bi + fi * br;
        Ct[((size_t)(l * PD + p)) * 128 + c]      = Cre[(l * HD + c) * PD + p];
        Ct[((size_t)(l * PD + p)) * 128 + 64 + c] = Cim[(l * HD + c) * PD + p];
    }
    for (int idx = tid; idx < NLAY * HD * HD; idx += 512) {
        int l = idx >> 12; int k = (idx >> 6) & 63; int c = idx & 63;
        w1t[idx] = w1[(l * HD + c) * HD + k];
        w2t[idx] = w2[(l * HD + c) * HD + k];
    }
    int g = gptr[0];
    for (int idx = tid; idx < IN_DIM * HD; idx += 512) {
        int k = idx >> 6, ch = idx & 63;
        wenc[idx] = (ch < 56) ? enc_w[((size_t)(g * 56 + ch)) * IN_DIM + k] : 0.0f;
    }
}

// ---------------------------------------------------------------- K1: encoder
// 512 blocks x 256 threads (4 waves = 4 channel-groups of 16). lane = row base,
// R=4 rows/thread (lane, +64, +128, +192) -> 256-row blocks. x tiles (32 cols)
// staged XOR-swizzled in LDS; weights staged per-tile in LDS, read broadcast.
__global__ __launch_bounds__(256, 4) void ssm_k1_encoder(
    const float* __restrict__ x, const int* __restrict__ gptr,
    const float* __restrict__ wenc, const float* __restrict__ enc_b,
    const float* __restrict__ ctx_emb,
    float* __restrict__ h, float* __restrict__ stats)
{
    __shared__ float xt[256 * 32];   // 32 KB, XOR-swizzled float4 slots
    __shared__ float wl[32 * 64];    // 8 KB per k-tile
    __shared__ float sp1[64], sp2[64];
    int tid = threadIdx.x;
    int lane = tid & 63, wid = tid >> 6;
    int ucg = __builtin_amdgcn_readfirstlane(wid);
    int g = gptr[0];
    size_t r0 = (size_t)blockIdx.x * 256;

    float acc[4][16];
#pragma unroll
    for (int i = 0; i < 16; ++i) {
        int ch = ucg * 16 + i;
        float b = (ch < 56) ? enc_b[g * 56 + ch] : 0.0f;
#pragma unroll
        for (int s = 0; s < 4; ++s) acc[s][i] = b;
    }

    for (int kt = 0; kt < 8; ++kt) {
        __syncthreads();
        // stage x: 256 rows x 32 cols (4096 float2), swizzle float4 slot by row&7
#pragma unroll
        for (int it = 0; it < 16; ++it) {
            int idx = it * 256 + tid;
            int rr = idx >> 4, c2 = idx & 15;
            float2 v = *(const float2*)&x[(r0 + rr) * IN_DIM + kt * 32 + c2 * 2];
            int c4 = (c2 >> 1) ^ (rr & 7);
            *(float2*)&xt[rr * 32 + c4 * 4 + (c2 & 1) * 2] = v;
        }
        // stage weights: wl[k][c], k = 0..31
#pragma unroll
        for (int it = 0; it < 8; ++it) {
            int idx = it * 256 + tid;
            wl[idx] = wenc[(size_t)kt * 2048 + idx];
        }
        __syncthreads();
        for (int k4 = 0; k4 < 8; ++k4) {
            float4 xv[4];
#pragma unroll
            for (int s = 0; s < 4; ++s)
                xv[s] = *(const float4*)&xt[(lane + 64 * s) * 32 + ((k4 ^ (lane & 7)) * 4)];
#pragma unroll
            for (int kk = 0; kk < 4; ++kk) {
                float wv[16];
                const float* wp = &wl[(k4 * 4 + kk) * 64 + ucg * 16];
                *(float4*)&wv[0]  = *(const float4*)&wp[0];
                *(float4*)&wv[4]  = *(const float4*)&wp[4];
                *(float4*)&wv[8]  = *(const float4*)&wp[8];
                *(float4*)&wv[12] = *(const float4*)&wp[12];
#pragma unroll
                for (int s = 0; s < 4; ++s) {
                    float xk = compsel(xv[s], kk);
#pragma unroll
                    for (int i = 0; i < 16; ++i) acc[s][i] += xk * wv[i];
                }
            }
        }
    }
    // ctx channels (56..63) override
    if (ucg == 3) {
#pragma unroll
        for (int i = 8; i < 16; ++i) {
            float cv = ctx_emb[g * 8 + (i - 8)];
#pragma unroll
            for (int s = 0; s < 4; ++s) acc[s][i] = cv;
        }
    }
    // write h
#pragma unroll
    for (int s = 0; s < 4; ++s) {
        int row = lane + 64 * s;
#pragma unroll
        for (int j4 = 0; j4 < 4; ++j4)
            *(float4*)&h[(r0 + row) * HD + ucg * 16 + j4 * 4] =
                make_float4(acc[s][j4 * 4], acc[s][j4 * 4 + 1],
                            acc[s][j4 * 4 + 2], acc[s][j4 * 4 + 3]);
    }
    // layer-0 stats: wave covers 256 rows (4 per lane)
#pragma unroll
    for (int i = 0; i < 16; ++i) {
        float v1 = acc[0][i] + acc[1][i] + acc[2][i] + acc[3][i];
        float v2 = acc[0][i] * acc[0][i] + acc[1][i] * acc[1][i]
                 + acc[2][i] * acc[2][i] + acc[3][i] * acc[3][i];
#pragma unroll
        for (int m = 1; m < 64; m <<= 1) { v1 += __shfl_xor(v1, m, 64); v2 += __shfl_xor(v2, m, 64); }
        if (lane == 0) { sp1[wid * 16 + i] = v1; sp2[wid * 16 + i] = v2; }
    }
    __syncthreads();
    if (tid < 64) {
        atomicAdd(&stats[tid],      sp1[tid]);
        atomicAdd(&stats[64 + tid], sp2[tid]);
    }
}

// ---------------------------------------------------------------- K2: hn -> Bu -> local scan
// 512 blocks x 512 threads (8 waves = 8 output-octets). R=4 rows/thread ->
// 256-row blocks = two 128-row scan chunks. Bbar staged in LDS.
__global__ __launch_bounds__(512, 2) void ssm_k2_bu_scan(
    const float* __restrict__ h, const float* __restrict__ stats,
    const float* __restrict__ nscale, const float* __restrict__ nbias,
    const float* __restrict__ Bbar_t, const float* __restrict__ Lbar,
    float* __restrict__ xs, float* __restrict__ carry, int l)
{
    __shared__ float buf[256 * BSTR];   // 69.6 KB
    __shared__ float bl[64 * 64];       // 16 KB
    __shared__ float sa[HD], sb[HD];
    int tid = threadIdx.x;
    int lane = tid & 63, wid = tid >> 6;
    int uco = __builtin_amdgcn_readfirstlane(wid);   // output octet 0..7
    size_t r0 = (size_t)blockIdx.x * 256;

    if (tid < HD) {
        float s1 = stats[l * 128 + tid], s2 = stats[l * 128 + 64 + tid];
        float mu = s1 * (1.0f / T_LEN);
        float var = fmaxf(s2 * (1.0f / T_LEN) - mu * mu, 0.0f);
        float sc = nscale[l * HD + tid] * rsqrtf(var + 1e-5f);
        sa[tid] = sc;
        sb[tid] = nbias[l * HD + tid] - mu * sc;
    }
#pragma unroll
    for (int it = 0; it < 8; ++it) {
        int idx = it * 512 + tid;
        bl[idx] = Bbar_t[(size_t)l * 4096 + idx];
    }
    __syncthreads();

    // hn for my 8 channels, 4 rows -> buf
#pragma unroll
    for (int s = 0; s < 4; ++s) {
        int row = lane + 64 * s;
        float4 h0 = *(const float4*)&h[(r0 + row) * HD + uco * 8];
        float4 h1 = *(const float4*)&h[(r0 + row) * HD + uco * 8 + 4];
        float hv[8];
        *(float4*)&hv[0] = h0; *(float4*)&hv[4] = h1;
        float o[8];
#pragma unroll
        for (int i = 0; i < 8; ++i) { int c = uco * 8 + i; o[i] = hv[i] * sa[c] + sb[c]; }
        *(float4*)&buf[row * BSTR + uco * 8]     = make_float4(o[0], o[1], o[2], o[3]);
        *(float4*)&buf[row * BSTR + uco * 8 + 4] = make_float4(o[4], o[5], o[6], o[7]);
    }
    __syncthreads();

    // Bu: bacc[s][j] over 64 input channels, k4-blocked
    float bacc[4][8];
#pragma unroll
    for (int s = 0; s < 4; ++s)
#pragma unroll
        for (int j = 0; j < 8; ++j) bacc[s][j] = 0.0f;
    for (int k4 = 0; k4 < 16; ++k4) {
        float4 hk[4];
#pragma unroll
        for (int s = 0; s < 4; ++s)
            hk[s] = *(const float4*)&buf[(lane + 64 * s) * BSTR + k4 * 4];
#pragma unroll
        for (int kk = 0; kk < 4; ++kk) {
            float wv[8];
            const float* bp = &bl[(k4 * 4 + kk) * 64 + uco * 8];
            *(float4*)&wv[0] = *(const float4*)&bp[0];
            *(float4*)&wv[4] = *(const float4*)&bp[4];
#pragma unroll
            for (int s = 0; s < 4; ++s) {
                float xk = compsel(hk[s], kk);
#pragma unroll
                for (int j = 0; j < 8; ++j) bacc[s][j] += xk * wv[j];
            }
        }
    }
    __syncthreads();   // hn reads done before overwriting with Bu
#pragma unroll
    for (int s = 0; s < 4; ++s) {
        int row = lane + 64 * s;
        *(float4*)&buf[row * BSTR + uco * 8]     = make_float4(bacc[s][0], bacc[s][1], bacc[s][2], bacc[s][3]);
        *(float4*)&buf[row * BSTR + uco * 8 + 4] = make_float4(bacc[s][4], bacc[s][5], bacc[s][6], bacc[s][7]);
    }
    __syncthreads();

    // in-chunk scans: wave 0 -> chunk 0, wave 1 -> chunk 1
    if (tid < 128) {
        int cid = tid >> 6;
        int slot = tid & 63;
        int p = slot >> 1;
        float Lr = Lbar[(l * PD + p) * 2];
        float Lj = Lbar[(l * PD + p) * 2 + 1];
        float csn = (slot & 1) ? Lj : -Lj;
        float xv = 0.0f;
        int base = cid * 128;
        for (int t = 0; t < CHUNK; ++t) {
            float b = buf[(base + t) * BSTR + slot];
            float xo = __shfl_xor(xv, 1, 64);
            xv = Lr * xv + csn * xo + b;
            buf[(base + t) * BSTR + slot] = xv;
        }
        carry[((size_t)blockIdx.x * 2 + cid) * 64 + slot] = xv;
    }
    __syncthreads();
#pragma unroll
    for (int s = 0; s < 4; ++s) {
        int row = lane + 64 * s;
#pragma unroll
        for (int q = 0; q < 2; ++q) {
            float4 v = *(float4*)&buf[row * BSTR + uco * 8 + q * 4];
            *(float4*)&xs[(r0 + row) * HD + uco * 8 + q * 4] = v;
        }
    }
}

// ---------------------------------------------------------------- K3: cross-chunk carry scan (unchanged)
__global__ __launch_bounds__(64) void ssm_k3_carry(
    const float* __restrict__ carry, const float* __restrict__ Ldt,
    float* __restrict__ pc, int l)
{
    int p = blockIdx.x;
    int lane = threadIdx.x;
    float ldr = Ldt[(l * PD + p) * 2], ldi = Ldt[(l * PD + p) * 2 + 1];
    float er = __expf(ldr * (float)CHUNK);
    float an = ldi * (float)CHUNK;
    float lcr = er * __cosf(an), lci = er * __sinf(an);   // L^CHUNK
    float cr[16], ci[16];
#pragma unroll
    for (int j = 0; j < 16; ++j) {
        cr[j] = carry[(size_t)(lane * 16 + j) * 64 + 2 * p];
        ci[j] = carry[(size_t)(lane * 16 + j) * 64 + 2 * p + 1];
    }
    float ur = 0.0f, ui = 0.0f;
#pragma unroll
    for (int j = 0; j < 16; ++j) {
        float nr = lcr * ur - lci * ui + cr[j];
        float ni = lcr * ui + lci * ur + ci[j];
        ur = nr; ui = ni;
    }
    float mr = lcr, mi = lci;
#pragma unroll
    for (int s = 0; s < 4; ++s) { float t = mr * mr - mi * mi; mi = 2.0f * mr * mi; mr = t; }
#pragma unroll
    for (int d = 1; d < 64; d <<= 1) {
        float tr = __shfl_up(ur, d, 64);
        float ti = __shfl_up(ui, d, 64);
        if (lane >= d) { ur = mr * tr - mi * ti + ur; ui = mr * ti + mi * tr + ui; }
        float t = mr * mr - mi * mi; mi = 2.0f * mr * mi; mr = t;
    }
    float pr = __shfl_up(ur, 1, 64), pi = __shfl_up(ui, 1, 64);
    float xr = (lane == 0) ? 0.0f : pr;
    float xi = (lane == 0) ? 0.0f : pi;
#pragma unroll
    for (int j = 0; j < 16; ++j) {
        pc[(size_t)(lane * 16 + j) * 64 + 2 * p]     = xr;
        pc[(size_t)(lane * 16 + j) * 64 + 2 * p + 1] = xi;
        float nr = lcr * xr - lci * xi + cr[j];
        float ni = lcr * xi + lci * xr + ci[j];
        xr = nr; xi = ni;
    }
}

// ---------------------------------------------------------------- K4: fixup + C-proj + gelu + GLU + residual (+stats / decoder)
// 512 blocks x 512 threads (8 waves = 8 ch-octets). R=4 rows -> 256-row blocks.
// ct then w1/w2 staged into one reused 32KB LDS region.
template <bool LAST>
__global__ __launch_bounds__(512, 2) void ssm_k4_out(
    const float* __restrict__ h, const float* __restrict__ xs,
    const float* __restrict__ pc, const float* __restrict__ stats,
    const float* __restrict__ nscale, const float* __restrict__ nbias,
    const float* __restrict__ Ldt, const float* __restrict__ Ct,
    const float* __restrict__ Dv,
    const float* __restrict__ w1t, const float* __restrict__ b1,
    const float* __restrict__ w2t, const float* __restrict__ b2,
    float* __restrict__ hout, float* __restrict__ stats_next,
    const float* __restrict__ dec_w, const float* __restrict__ dec_b,
    float* __restrict__ outp, int l)
{
    __shared__ float buf[256 * BSTR];   // 69.6 KB
    __shared__ float wbuf[8192];        // 32 KB (ct, then w1|w2)
    __shared__ float sa[HD], sb[HD];
    __shared__ float sp1[64], sp2[64];
    int tid = threadIdx.x;
    int lane = tid & 63, wid = tid >> 6;
    int uco = __builtin_amdgcn_readfirstlane(wid);
    size_t r0 = (size_t)blockIdx.x * 256;

    if (tid < HD) {
        float s1 = stats[l * 128 + tid], s2 = stats[l * 128 + 64 + tid];
        float mu = s1 * (1.0f / T_LEN);
        float var = fmaxf(s2 * (1.0f / T_LEN) - mu * mu, 0.0f);
        float sc = nscale[l * HD + tid] * rsqrtf(var + 1e-5f);
        sa[tid] = sc;
        sb[tid] = nbias[l * HD + tid] - mu * sc;
    }
    // stage ct
#pragma unroll
    for (int it = 0; it < 8; ++it) {
        int idx = it * 512 + tid;
        wbuf[idx] = Ct[(size_t)l * 4096 + idx];
    }
    // xs + carry fixup -> buf
    {
        float ld[8];
        const float* ldp = &Ldt[(l * PD + uco * 4) * 2];
#pragma unroll
        for (int j = 0; j < 8; ++j) ld[j] = ldp[j];
#pragma unroll
        for (int s = 0; s < 4; ++s) {
            int row = lane + 64 * s;
            size_t grow = r0 + row;
            float4 v0 = *(const float4*)&xs[grow * HD + uco * 8];
            float4 v1 = *(const float4*)&xs[grow * HD + uco * 8 + 4];
            const float* pcp = &pc[(grow >> 7) * HD + uco * 8];
            float tt = (float)((int)(grow & 127) + 1);
            float xf[8];
            *(float4*)&xf[0] = v0; *(float4*)&xf[4] = v1;
#pragma unroll
            for (int pp = 0; pp < 4; ++pp) {
                float e = __expf(ld[2 * pp] * tt);
                float an = ld[2 * pp + 1] * tt;
                float prr = e * __cosf(an), pri = e * __sinf(an);
                float pr_ = pcp[2 * pp], pi_ = pcp[2 * pp + 1];
                xf[2 * pp]     += prr * pr_ - pri * pi_;
                xf[2 * pp + 1] += prr * pi_ + pri * pr_;
            }
            *(float4*)&buf[row * BSTR + uco * 8]     = make_float4(xf[0], xf[1], xf[2], xf[3]);
            *(float4*)&buf[row * BSTR + uco * 8 + 4] = make_float4(xf[4], xf[5], xf[6], xf[7]);
        }
    }
    __syncthreads();

    // C projection, p-pair blocked
    float y[4][8];
#pragma unroll
    for (int s = 0; s < 4; ++s)
#pragma unroll
        for (int i = 0; i < 8; ++i) y[s][i] = 0.0f;
    for (int p2 = 0; p2 < 16; ++p2) {
        float4 xv[4];
#pragma unroll
        for (int s = 0; s < 4; ++s)
            xv[s] = *(const float4*)&buf[(lane + 64 * s) * BSTR + p2 * 4];
        float r0v[8], i0v[8], r1v[8], i1v[8];
        const float* cp0 = &wbuf[(2 * p2) * 128 + uco * 8];
        const float* cp1 = &wbuf[(2 * p2 + 1) * 128 + uco * 8];
        *(float4*)&r0v[0] = *(const float4*)&cp0[0];  *(float4*)&r0v[4] = *(const float4*)&cp0[4];
        *(float4*)&i0v[0] = *(const float4*)&cp0[64]; *(float4*)&i0v[4] = *(const float4*)&cp0[68];
        *(float4*)&r1v[0] = *(const float4*)&cp1[0];  *(float4*)&r1v[4] = *(const float4*)&cp1[4];
        *(float4*)&i1v[0] = *(const float4*)&cp1[64]; *(float4*)&i1v[4] = *(const float4*)&cp1[68];
#pragma unroll
        for (int s = 0; s < 4; ++s) {
#pragma unroll
            for (int i = 0; i < 8; ++i)
                y[s][i] += xv[s].x * r0v[i] - xv[s].y * i0v[i]
                         + xv[s].z * r1v[i] - xv[s].w * i1v[i];
        }
    }

    // h rows + gelu(2y + hn*D)
    float hrow[4][8], gg[4][8];
    {
        float dv[8], sav[8], sbv[8];
        const float* dvp = &Dv[l * HD + uco * 8];
#pragma unroll
        for (int j = 0; j < 8; ++j) {
            dv[j] = dvp[j];
            sav[j] = sa[uco * 8 + j];
            sbv[j] = sb[uco * 8 + j];
        }
#pragma unroll
        for (int s = 0; s < 4; ++s) {
            int row = lane + 64 * s;
            float4 h0 = *(const float4*)&h[(r0 + row) * HD + uco * 8];
            float4 h1 = *(const float4*)&h[(r0 + row) * HD + uco * 8 + 4];
            *(float4*)&hrow[s][0] = h0; *(float4*)&hrow[s][4] = h1;
#pragma unroll
            for (int i = 0; i < 8; ++i) {
                float hnv = hrow[s][i] * sav[i] + sbv[i];
                float t = 2.0f * y[s][i] + hnv * dv[i];
                float u2 = 1.5957691216057308f * (t + 0.044715f * t * t * t);
                gg[s][i] = t / (1.0f + __expf(-u2));
            }
        }
    }
    __syncthreads();   // all C-proj buf reads + ct reads done
    // write g; stage w1/w2 over ct
#pragma unroll
    for (int s = 0; s < 4; ++s) {
        int row = lane + 64 * s;
        *(float4*)&buf[row * BSTR + uco * 8]     = make_float4(gg[s][0], gg[s][1], gg[s][2], gg[s][3]);
        *(float4*)&buf[row * BSTR + uco * 8 + 4] = make_float4(gg[s][4], gg[s][5], gg[s][6], gg[s][7]);
    }
#pragma unroll
    for (int it = 0; it < 8; ++it) {
        int idx = it * 512 + tid;
        wbuf[idx]        = w1t[(size_t)l * 4096 + idx];
        wbuf[4096 + idx] = w2t[(size_t)l * 4096 + idx];
    }
    __syncthreads();

    // GLU, k4-blocked
    float uacc[4][8], sacc[4][8];
    {
        float bb1[8], bb2[8];
        const float* b1p = &b1[l * HD + uco * 8];
        const float* b2p = &b2[l * HD + uco * 8];
#pragma unroll
        for (int j = 0; j < 8; ++j) { bb1[j] = b1p[j]; bb2[j] = b2p[j]; }
#pragma unroll
        for (int s = 0; s < 4; ++s)
#pragma unroll
            for (int j = 0; j < 8; ++j) { uacc[s][j] = bb1[j]; sacc[s][j] = bb2[j]; }
    }
    for (int k4 = 0; k4 < 16; ++k4) {
        float4 gk[4];
#pragma unroll
        for (int s = 0; s < 4; ++s)
            gk[s] = *(const float4*)&buf[(lane + 64 * s) * BSTR + k4 * 4];
#pragma unroll
        for (int kk = 0; kk < 4; ++kk) {
            float av[8], cv[8];
            const float* p1w = &wbuf[(k4 * 4 + kk) * 64 + uco * 8];
            const float* p2w = &wbuf[4096 + (k4 * 4 + kk) * 64 + uco * 8];
            *(float4*)&av[0] = *(const float4*)&p1w[0];
            *(float4*)&av[4] = *(const float4*)&p1w[4];
            *(float4*)&cv[0] = *(const float4*)&p2w[0];
            *(float4*)&cv[4] = *(const float4*)&p2w[4];
#pragma unroll
            for (int s = 0; s < 4; ++s) {
                float gv = compsel(gk[s], kk);
#pragma unroll
                for (int j = 0; j < 8; ++j) {
                    uacc[s][j] += gv * av[j];
                    sacc[s][j] += gv * cv[j];
                }
            }
        }
    }

    if (LAST) {
        float dw0[8], dw1[8];
#pragma unroll
        for (int j = 0; j < 8; ++j) {
            dw0[j] = dec_w[uco * 8 + j];
            dw1[j] = dec_w[64 + uco * 8 + j];
        }
        float db0 = dec_b[0], db1 = dec_b[1];
        __syncthreads();   // GLU wbuf reads done before reuse for partials
#pragma unroll
        for (int s = 0; s < 4; ++s) {
            int row = lane + 64 * s;
            float o0 = 0.0f, o1 = 0.0f;
#pragma unroll
            for (int i = 0; i < 8; ++i) {
                float sg = 1.0f / (1.0f + __expf(-sacc[s][i]));
                float ho = hrow[s][i] + uacc[s][i] * sg;
                o0 += ho * dw0[i];
                o1 += ho * dw1[i];
            }
            wbuf[row * 16 + uco * 2]     = o0;
            wbuf[row * 16 + uco * 2 + 1] = o1;
        }
        __syncthreads();
        if (tid < 256) {
            float a0 = 0.0f, a1 = 0.0f;
#pragma unroll
            for (int w = 0; w < 8; ++w) {
                a0 += wbuf[tid * 16 + 2 * w];
                a1 += wbuf[tid * 16 + 2 * w + 1];
            }
            *(float2*)&outp[(r0 + tid) * 2] = make_float2(a0 + db0, a1 + db1);
        }
    } else {
        float ho[4][8];
#pragma unroll
        for (int s = 0; s < 4; ++s) {
            int row = lane + 64 * s;
#pragma unroll
            for (int i = 0; i < 8; ++i) {
                float sg = 1.0f / (1.0f + __expf(-sacc[s][i]));
                ho[s][i] = hrow[s][i] + uacc[s][i] * sg;
            }
            *(float4*)&hout[(r0 + row) * HD + uco * 8] =
                make_float4(ho[s][0], ho[s][1], ho[s][2], ho[s][3]);
            *(float4*)&hout[(r0 + row) * HD + uco * 8 + 4] =
                make_float4(ho[s][4], ho[s][5], ho[s][6], ho[s][7]);
        }
        // next-layer stats: wave covers 256 rows
#pragma unroll
        for (int i = 0; i < 8; ++i) {
            float v1 = ho[0][i] + ho[1][i] + ho[2][i] + ho[3][i];
            float v2 = ho[0][i] * ho[0][i] + ho[1][i] * ho[1][i]
                     + ho[2][i] * ho[2][i] + ho[3][i] * ho[3][i];
#pragma unroll
            for (int m = 1; m < 64; m <<= 1) { v1 += __shfl_xor(v1, m, 64); v2 += __shfl_xor(v2, m, 64); }
            if (lane == 0) { sp1[wid * 8 + i] = v1; sp2[wid * 8 + i] = v2; }
        }
        __syncthreads();
        if (tid < 64) {
            atomicAdd(&stats_next[tid],      sp1[tid]);
            atomicAdd(&stats_next[64 + tid], sp2[tid]);
        }
    }
}

// ---------------------------------------------------------------- launch
extern "C" void kernel_launch(void* const* d_in, const int* in_sizes, int n_in,
                              void* d_out, int out_size, void* d_ws, size_t ws_size,
                              hipStream_t stream)
{
    (void)in_sizes; (void)n_in; (void)out_size; (void)ws_size;
    const float* x     = (const float*)d_in[0];
    const int*   gidx  = (const int*)d_in[1];
    const float* enc_w = (const float*)d_in[2];
    const float* enc_b = (const float*)d_in[3];
    const float* ctx   = (const float*)d_in[4];
    const float* Lre   = (const float*)d_in[5];
    const float* Lim   = (const float*)d_in[6];
    const float* Bre   = (const float*)d_in[7];
    const float* Bim   = (const float*)d_in[8];
    const float* Cre   = (const float*)d_in[9];
    const float* Cim   = (const float*)d_in[10];
    const float* Dv    = (const float*)d_in[11];
    const float* lstep = (const float*)d_in[12];
    const float* nsc   = (const float*)d_in[13];
    const float* nbi   = (const float*)d_in[14];
    const float* w1    = (const float*)d_in[15];
    const float* b1    = (const float*)d_in[16];
    const float* w2    = (const float*)d_in[17];
    const float* b2    = (const float*)d_in[18];
    const float* dw    = (const float*)d_in[19];
    const float* db    = (const float*)d_in[20];
    float* out = (float*)d_out;

    float* ws = (float*)d_ws;
    float* h      = ws;  ws += (size_t)T_LEN * HD;
    float* xs     = ws;  ws += (size_t)T_LEN * HD;
    float* carry  = ws;  ws += (size_t)NBLK * HD;
    float* pc     = ws;  ws += (size_t)NBLK * HD;
    float* stats  = ws;  ws += NLAY * 128;
    float* Lbar   = ws;  ws += NLAY * PD * 2;
    float* Ldt    = ws;  ws += NLAY * PD * 2;
    float* Bbar_t = ws;  ws += NLAY * HD * HD;
    float* Ct     = ws;  ws += NLAY * PD * 128;
    float* w1t    = ws;  ws += NLAY * HD * HD;
    float* w2t    = ws;  ws += NLAY * HD * HD;
    float* wenc   = ws;  ws += IN_DIM * HD;

    ssm_k0_setup<<<1, 512, 0, stream>>>(Lre, Lim, lstep, Bre, Bim, Cre, Cim, w1, w2,
                                        enc_w, gidx, Lbar, Ldt, Bbar_t, Ct, w1t, w2t,
                                        wenc, stats);
    ssm_k1_encoder<<<512, 256, 0, stream>>>(x, gidx, wenc, enc_b, ctx, h, stats);
    for (int l = 0; l < NLAY; ++l) {
        ssm_k2_bu_scan<<<512, 512, 0, stream>>>(h, stats, nsc, nbi, Bbar_t, Lbar, xs, carry, l);
        ssm_k3_carry<<<PD, 64, 0, stream>>>(carry, Ldt, pc, l);
        if (l < NLAY - 1) {
            ssm_k4_out<false><<<512, 512, 0, stream>>>(
                h, xs, pc, stats, nsc, nbi, Ldt, Ct, Dv, w1t, b1, w2t, b2,
                h, stats + (l + 1) * 128, dw, db, out, l);
        } else {
            ssm_k4_out<true><<<512, 512, 0, stream>>>(
                h, xs, pc, stats, nsc, nbi, Ldt, Ct, Dv, w1t, b1, w2t, b2,
                h, stats, dw, db, out, l);
        }
    }
}

// Round 7
// 547.397 us; speedup vs baseline: 2.5802x; 1.0633x over previous
//
#include <hip/hip_runtime.h>

#define T_LEN   131072
#define IN_DIM  256
#define HD      64
#define PD      32
#define NLAY    4
#define CHUNK   128
#define NBLK    (T_LEN / CHUNK)   // 1024
#define BSTR    68                // buf stride: 68 % 32 == 4 -> conflict-free b128 column reads
#define XSTR    36                // K1 x-tile stride: 36 % 32 == 4

__device__ __forceinline__ float compsel(float4 v, int kk) {
    return kk == 0 ? v.x : kk == 1 ? v.y : kk == 2 ? v.z : v.w;
}

// ---------------------------------------------------------------- K0: setup
__global__ __launch_bounds__(512) void ssm_k0_setup(
    const float* __restrict__ Lre, const float* __restrict__ Lim,
    const float* __restrict__ logstep,
    const float* __restrict__ Bre, const float* __restrict__ Bim,
    const float* __restrict__ Cre, const float* __restrict__ Cim,
    const float* __restrict__ w1, const float* __restrict__ w2,
    const float* __restrict__ enc_w, const int* __restrict__ gptr,
    float* __restrict__ Lbar, float* __restrict__ Ldt,
    float* __restrict__ Bbar_t, float* __restrict__ Ct,
    float* __restrict__ w1t, float* __restrict__ w2t,
    float* __restrict__ wenc, float* __restrict__ stats)
{
    __shared__ float fact[NLAY * PD * 2];
    int tid = threadIdx.x;
    if (tid < NLAY * PD) {
        int l = tid >> 5, p = tid & 31;
        float dt = expf(logstep[l * PD + p]);
        float lr = Lre[l * PD + p], li = Lim[l * PD + p];
        float ldr = lr * dt, ldi = li * dt;
        Ldt[tid * 2] = ldr; Ldt[tid * 2 + 1] = ldi;
        float e = expf(ldr);
        float sn, cs; sincosf(ldi, &sn, &cs);
        float lbr = e * cs, lbi = e * sn;
        Lbar[tid * 2] = lbr; Lbar[tid * 2 + 1] = lbi;
        float den = lr * lr + li * li;
        float nr = lbr - 1.0f, ni = lbi;
        fact[tid * 2]     = (nr * lr + ni * li) / den;
        fact[tid * 2 + 1] = (ni * lr - nr * li) / den;
    }
    if (tid < NLAY * 128) stats[tid] = 0.0f;
    __syncthreads();
    // Bbar_t[l][k=c][2p] ; Ct planes [l][p][re:0..63 | im:64..127]
    for (int idx = tid; idx < NLAY * PD * HD; idx += 512) {
        int lp = idx >> 6; int c = idx & 63;
        int l = lp >> 5, p = lp & 31;
        float fr = fact[lp * 2], fi = fact[lp * 2 + 1];
        float br = Bre[idx], bi = Bim[idx];                    // B is [l][p][h]
        Bbar_t[((size_t)(l * HD + c)) * HD + 2 * p]     = fr * br - fi * bi;
        Bbar_t[((size_t)(l * HD + c)) * HD + 2 * p + 1] = fr * bi + fi * br;
        Ct[((size_t)(l * PD + p)) * 128 + c]      = Cre[(l * HD + c) * PD + p];
        Ct[((size_t)(l * PD + p)) * 128 + 64 + c] = Cim[(l * HD + c) * PD + p];
    }
    for (int idx = tid; idx < NLAY * HD * HD; idx += 512) {
        int l = idx >> 12; int k = (idx >> 6) & 63; int c = idx & 63;
        w1t[idx] = w1[(l * HD + c) * HD + k];
        w2t[idx] = w2[(l * HD + c) * HD + k];
    }
    int g = gptr[0];
    for (int idx = tid; idx < IN_DIM * HD; idx += 512) {
        int k = idx >> 6, ch = idx & 63;
        wenc[idx] = (ch < 56) ? enc_w[((size_t)(g * 56 + ch)) * IN_DIM + k] : 0.0f;
    }
}

// ---------------------------------------------------------------- K1: encoder
// 512 blocks x 256 threads (4 waves = 4 ch-groups of 16). R=4 rows/thread ->
// 256-row blocks. x tile [256][XSTR=36] (conflict-free b128 column reads);
// weights staged per-kt (8KB), read wave-uniform (broadcast).
__global__ __launch_bounds__(256, 3) void ssm_k1_encoder(
    const float* __restrict__ x, const int* __restrict__ gptr,
    const float* __restrict__ wenc, const float* __restrict__ enc_b,
    const float* __restrict__ ctx_emb,
    float* __restrict__ h, float* __restrict__ stats)
{
    __shared__ float xt[256 * XSTR];   // 36864 B
    __shared__ float wl[32 * 64];      // 8192 B
    __shared__ float sp1[64], sp2[64];
    int tid = threadIdx.x;
    int lane = tid & 63, wid = tid >> 6;
    int ucg = __builtin_amdgcn_readfirstlane(wid);
    int g = gptr[0];
    size_t r0 = (size_t)blockIdx.x * 256;

    float acc[4][16];
#pragma unroll
    for (int i = 0; i < 16; ++i) {
        int ch = ucg * 16 + i;
        float b = (ch < 56) ? enc_b[g * 56 + ch] : 0.0f;
#pragma unroll
        for (int s = 0; s < 4; ++s) acc[s][i] = b;
    }

    for (int kt = 0; kt < 8; ++kt) {
        __syncthreads();
        // x: 256 rows x 32 cols = 4096 float2
#pragma unroll
        for (int it = 0; it < 16; ++it) {
            int idx = it * 256 + tid;
            int rr = idx >> 4, c2 = idx & 15;
            *(float2*)&xt[rr * XSTR + c2 * 2] =
                *(const float2*)&x[(r0 + rr) * IN_DIM + kt * 32 + c2 * 2];
        }
        // weights: 2048 floats = 512 float4
#pragma unroll
        for (int it = 0; it < 2; ++it) {
            int idx = it * 256 + tid;
            *(float4*)&wl[idx * 4] = *(const float4*)&wenc[(size_t)kt * 2048 + idx * 4];
        }
        __syncthreads();
        for (int k4 = 0; k4 < 8; ++k4) {
            float4 xv[4];
#pragma unroll
            for (int s = 0; s < 4; ++s)
                xv[s] = *(const float4*)&xt[(lane + 64 * s) * XSTR + k4 * 4];
#pragma unroll
            for (int kk = 0; kk < 4; ++kk) {
                float wv[16];
                const float* wp = &wl[(k4 * 4 + kk) * 64 + ucg * 16];   // uniform
                *(float4*)&wv[0]  = *(const float4*)&wp[0];
                *(float4*)&wv[4]  = *(const float4*)&wp[4];
                *(float4*)&wv[8]  = *(const float4*)&wp[8];
                *(float4*)&wv[12] = *(const float4*)&wp[12];
#pragma unroll
                for (int s = 0; s < 4; ++s) {
                    float xk = compsel(xv[s], kk);
#pragma unroll
                    for (int i = 0; i < 16; ++i) acc[s][i] += xk * wv[i];
                }
            }
        }
    }
    // ctx channels (56..63)
    if (ucg == 3) {
#pragma unroll
        for (int i = 8; i < 16; ++i) {
            float cv = ctx_emb[g * 8 + (i - 8)];
#pragma unroll
            for (int s = 0; s < 4; ++s) acc[s][i] = cv;
        }
    }
#pragma unroll
    for (int s = 0; s < 4; ++s) {
        int row = lane + 64 * s;
#pragma unroll
        for (int j4 = 0; j4 < 4; ++j4)
            *(float4*)&h[(r0 + row) * HD + ucg * 16 + j4 * 4] =
                make_float4(acc[s][j4 * 4], acc[s][j4 * 4 + 1],
                            acc[s][j4 * 4 + 2], acc[s][j4 * 4 + 3]);
    }
#pragma unroll
    for (int i = 0; i < 16; ++i) {
        float v1 = acc[0][i] + acc[1][i] + acc[2][i] + acc[3][i];
        float v2 = acc[0][i] * acc[0][i] + acc[1][i] * acc[1][i]
                 + acc[2][i] * acc[2][i] + acc[3][i] * acc[3][i];
#pragma unroll
        for (int m = 1; m < 64; m <<= 1) { v1 += __shfl_xor(v1, m, 64); v2 += __shfl_xor(v2, m, 64); }
        if (lane == 0) { sp1[wid * 16 + i] = v1; sp2[wid * 16 + i] = v2; }
    }
    __syncthreads();
    if (tid < 64) {
        atomicAdd(&stats[tid],      sp1[tid]);
        atomicAdd(&stats[64 + tid], sp2[tid]);
    }
}

// ---------------------------------------------------------------- K2: hn -> Bu -> local scan
// 1024 blocks x 512 threads (8 waves = 8 ch-octets), 128-row blocks, R=2.
__global__ __launch_bounds__(512, 4) void ssm_k2_bu_scan(
    const float* __restrict__ h, const float* __restrict__ stats,
    const float* __restrict__ nscale, const float* __restrict__ nbias,
    const float* __restrict__ Bbar_t, const float* __restrict__ Lbar,
    float* __restrict__ xs, float* __restrict__ carry, int l)
{
    __shared__ float buf[128 * BSTR];   // 34816 B
    __shared__ float bl[64 * 64];       // 16384 B
    __shared__ float sa[HD], sb[HD];
    int tid = threadIdx.x;
    int lane = tid & 63, wid = tid >> 6;
    int uco = __builtin_amdgcn_readfirstlane(wid);
    size_t r0 = (size_t)blockIdx.x * CHUNK;

    if (tid < HD) {
        float s1 = stats[l * 128 + tid], s2 = stats[l * 128 + 64 + tid];
        float mu = s1 * (1.0f / T_LEN);
        float var = fmaxf(s2 * (1.0f / T_LEN) - mu * mu, 0.0f);
        float sc = nscale[l * HD + tid] * rsqrtf(var + 1e-5f);
        sa[tid] = sc;
        sb[tid] = nbias[l * HD + tid] - mu * sc;
    }
#pragma unroll
    for (int it = 0; it < 2; ++it) {
        int idx = it * 512 + tid;
        *(float4*)&bl[idx * 4] = *(const float4*)&Bbar_t[(size_t)l * 4096 + idx * 4];
    }
    __syncthreads();

    // hn -> buf
#pragma unroll
    for (int s = 0; s < 2; ++s) {
        int row = lane + 64 * s;
        float4 h0 = *(const float4*)&h[(r0 + row) * HD + uco * 8];
        float4 h1 = *(const float4*)&h[(r0 + row) * HD + uco * 8 + 4];
        float hv[8];
        *(float4*)&hv[0] = h0; *(float4*)&hv[4] = h1;
        float o[8];
#pragma unroll
        for (int i = 0; i < 8; ++i) { int c = uco * 8 + i; o[i] = hv[i] * sa[c] + sb[c]; }
        *(float4*)&buf[row * BSTR + uco * 8]     = make_float4(o[0], o[1], o[2], o[3]);
        *(float4*)&buf[row * BSTR + uco * 8 + 4] = make_float4(o[4], o[5], o[6], o[7]);
    }
    __syncthreads();

    float bacc[2][8];
#pragma unroll
    for (int s = 0; s < 2; ++s)
#pragma unroll
        for (int j = 0; j < 8; ++j) bacc[s][j] = 0.0f;
    for (int k4 = 0; k4 < 16; ++k4) {
        float4 hk[2];
#pragma unroll
        for (int s = 0; s < 2; ++s)
            hk[s] = *(const float4*)&buf[(lane + 64 * s) * BSTR + k4 * 4];
#pragma unroll
        for (int kk = 0; kk < 4; ++kk) {
            float wv[8];
            const float* bp = &bl[(k4 * 4 + kk) * 64 + uco * 8];   // uniform
            *(float4*)&wv[0] = *(const float4*)&bp[0];
            *(float4*)&wv[4] = *(const float4*)&bp[4];
#pragma unroll
            for (int s = 0; s < 2; ++s) {
                float xk = compsel(hk[s], kk);
#pragma unroll
                for (int j = 0; j < 8; ++j) bacc[s][j] += xk * wv[j];
            }
        }
    }
    __syncthreads();
#pragma unroll
    for (int s = 0; s < 2; ++s) {
        int row = lane + 64 * s;
        *(float4*)&buf[row * BSTR + uco * 8]     = make_float4(bacc[s][0], bacc[s][1], bacc[s][2], bacc[s][3]);
        *(float4*)&buf[row * BSTR + uco * 8 + 4] = make_float4(bacc[s][4], bacc[s][5], bacc[s][6], bacc[s][7]);
    }
    __syncthreads();

    if (tid < 64) {
        int p = lane >> 1;
        float Lr = Lbar[(l * PD + p) * 2];
        float Lj = Lbar[(l * PD + p) * 2 + 1];
        float csn = (lane & 1) ? Lj : -Lj;
        float xv = 0.0f;
        for (int t = 0; t < CHUNK; ++t) {
            float b = buf[t * BSTR + lane];
            float xo = __shfl_xor(xv, 1, 64);
            xv = Lr * xv + csn * xo + b;
            buf[t * BSTR + lane] = xv;
        }
        carry[(size_t)blockIdx.x * 64 + lane] = xv;
    }
    __syncthreads();
#pragma unroll
    for (int s = 0; s < 2; ++s) {
        int row = lane + 64 * s;
#pragma unroll
        for (int q = 0; q < 2; ++q)
            *(float4*)&xs[(r0 + row) * HD + uco * 8 + q * 4] =
                *(float4*)&buf[row * BSTR + uco * 8 + q * 4];
    }
}

// ---------------------------------------------------------------- K3: cross-chunk carry scan (unchanged)
__global__ __launch_bounds__(64) void ssm_k3_carry(
    const float* __restrict__ carry, const float* __restrict__ Ldt,
    float* __restrict__ pc, int l)
{
    int p = blockIdx.x;
    int lane = threadIdx.x;
    float ldr = Ldt[(l * PD + p) * 2], ldi = Ldt[(l * PD + p) * 2 + 1];
    float er = __expf(ldr * (float)CHUNK);
    float an = ldi * (float)CHUNK;
    float lcr = er * __cosf(an), lci = er * __sinf(an);   // L^CHUNK
    float cr[16], ci[16];
#pragma unroll
    for (int j = 0; j < 16; ++j) {
        cr[j] = carry[(size_t)(lane * 16 + j) * 64 + 2 * p];
        ci[j] = carry[(size_t)(lane * 16 + j) * 64 + 2 * p + 1];
    }
    float ur = 0.0f, ui = 0.0f;
#pragma unroll
    for (int j = 0; j < 16; ++j) {
        float nr = lcr * ur - lci * ui + cr[j];
        float ni = lcr * ui + lci * ur + ci[j];
        ur = nr; ui = ni;
    }
    float mr = lcr, mi = lci;
#pragma unroll
    for (int s = 0; s < 4; ++s) { float t = mr * mr - mi * mi; mi = 2.0f * mr * mi; mr = t; }
#pragma unroll
    for (int d = 1; d < 64; d <<= 1) {
        float tr = __shfl_up(ur, d, 64);
        float ti = __shfl_up(ui, d, 64);
        if (lane >= d) { ur = mr * tr - mi * ti + ur; ui = mr * ti + mi * tr + ui; }
        float t = mr * mr - mi * mi; mi = 2.0f * mr * mi; mr = t;
    }
    float pr = __shfl_up(ur, 1, 64), pi = __shfl_up(ui, 1, 64);
    float xr = (lane == 0) ? 0.0f : pr;
    float xi = (lane == 0) ? 0.0f : pi;
#pragma unroll
    for (int j = 0; j < 16; ++j) {
        pc[(size_t)(lane * 16 + j) * 64 + 2 * p]     = xr;
        pc[(size_t)(lane * 16 + j) * 64 + 2 * p + 1] = xi;
        float nr = lcr * xr - lci * xi + cr[j];
        float ni = lcr * xi + lci * xr + ci[j];
        xr = nr; xi = ni;
    }
}

// ---------------------------------------------------------------- K4: fixup + C-proj + gelu + GLU + residual (+stats / decoder)
// 1024 blocks x 512 threads (8 waves = 8 ch-octets), 128-row blocks, R=2.
// wbuf 32KB: ct (16KB) then w1|w2 (32KB).
template <bool LAST>
__global__ __launch_bounds__(512, 4) void ssm_k4_out(
    const float* __restrict__ h, const float* __restrict__ xs,
    const float* __restrict__ pc, const float* __restrict__ stats,
    const float* __restrict__ nscale, const float* __restrict__ nbias,
    const float* __restrict__ Ldt, const float* __restrict__ Ct,
    const float* __restrict__ Dv,
    const float* __restrict__ w1t, const float* __restrict__ b1,
    const float* __restrict__ w2t, const float* __restrict__ b2,
    float* __restrict__ hout, float* __restrict__ stats_next,
    const float* __restrict__ dec_w, const float* __restrict__ dec_b,
    float* __restrict__ outp, int l)
{
    __shared__ float buf[128 * BSTR];   // 34816 B
    __shared__ float wbuf[8192];        // 32768 B
    __shared__ float sa[HD], sb[HD];
    __shared__ float sp1[64], sp2[64];
    int tid = threadIdx.x;
    int lane = tid & 63, wid = tid >> 6;
    int uco = __builtin_amdgcn_readfirstlane(wid);
    size_t r0 = (size_t)blockIdx.x * CHUNK;

    if (tid < HD) {
        float s1 = stats[l * 128 + tid], s2 = stats[l * 128 + 64 + tid];
        float mu = s1 * (1.0f / T_LEN);
        float var = fmaxf(s2 * (1.0f / T_LEN) - mu * mu, 0.0f);
        float sc = nscale[l * HD + tid] * rsqrtf(var + 1e-5f);
        sa[tid] = sc;
        sb[tid] = nbias[l * HD + tid] - mu * sc;
    }
    // stage ct
#pragma unroll
    for (int it = 0; it < 2; ++it) {
        int idx = it * 512 + tid;
        *(float4*)&wbuf[idx * 4] = *(const float4*)&Ct[(size_t)l * 4096 + idx * 4];
    }
    // xs + carry fixup -> buf
    {
        float ld[8];
        const float* ldp = &Ldt[(l * PD + uco * 4) * 2];   // uniform
#pragma unroll
        for (int j = 0; j < 8; ++j) ld[j] = ldp[j];
#pragma unroll
        for (int s = 0; s < 2; ++s) {
            int row = lane + 64 * s;
            size_t grow = r0 + row;
            float4 v0 = *(const float4*)&xs[grow * HD + uco * 8];
            float4 v1 = *(const float4*)&xs[grow * HD + uco * 8 + 4];
            const float* pcp = &pc[(size_t)blockIdx.x * HD + uco * 8];   // uniform
            float tt = (float)(row + 1);
            float xf[8];
            *(float4*)&xf[0] = v0; *(float4*)&xf[4] = v1;
#pragma unroll
            for (int pp = 0; pp < 4; ++pp) {
                float e = __expf(ld[2 * pp] * tt);
                float an = ld[2 * pp + 1] * tt;
                float prr = e * __cosf(an), pri = e * __sinf(an);
                float pr_ = pcp[2 * pp], pi_ = pcp[2 * pp + 1];
                xf[2 * pp]     += prr * pr_ - pri * pi_;
                xf[2 * pp + 1] += prr * pi_ + pri * pr_;
            }
            *(float4*)&buf[row * BSTR + uco * 8]     = make_float4(xf[0], xf[1], xf[2], xf[3]);
            *(float4*)&buf[row * BSTR + uco * 8 + 4] = make_float4(xf[4], xf[5], xf[6], xf[7]);
        }
    }
    __syncthreads();

    // C projection
    float y[2][8];
#pragma unroll
    for (int s = 0; s < 2; ++s)
#pragma unroll
        for (int i = 0; i < 8; ++i) y[s][i] = 0.0f;
    for (int p2 = 0; p2 < 16; ++p2) {
        float4 xv[2];
#pragma unroll
        for (int s = 0; s < 2; ++s)
            xv[s] = *(const float4*)&buf[(lane + 64 * s) * BSTR + p2 * 4];
        float r0v[8], i0v[8], r1v[8], i1v[8];
        const float* cp0 = &wbuf[(2 * p2) * 128 + uco * 8];       // uniform
        const float* cp1 = &wbuf[(2 * p2 + 1) * 128 + uco * 8];   // uniform
        *(float4*)&r0v[0] = *(const float4*)&cp0[0];  *(float4*)&r0v[4] = *(const float4*)&cp0[4];
        *(float4*)&i0v[0] = *(const float4*)&cp0[64]; *(float4*)&i0v[4] = *(const float4*)&cp0[68];
        *(float4*)&r1v[0] = *(const float4*)&cp1[0];  *(float4*)&r1v[4] = *(const float4*)&cp1[4];
        *(float4*)&i1v[0] = *(const float4*)&cp1[64]; *(float4*)&i1v[4] = *(const float4*)&cp1[68];
#pragma unroll
        for (int s = 0; s < 2; ++s)
#pragma unroll
            for (int i = 0; i < 8; ++i)
                y[s][i] += xv[s].x * r0v[i] - xv[s].y * i0v[i]
                         + xv[s].z * r1v[i] - xv[s].w * i1v[i];
    }

    // h rows + gelu(2y + hn*D)
    float hrow[2][8], gg[2][8];
    {
        float dv[8], sav[8], sbv[8];
        const float* dvp = &Dv[l * HD + uco * 8];   // uniform
#pragma unroll
        for (int j = 0; j < 8; ++j) {
            dv[j] = dvp[j];
            sav[j] = sa[uco * 8 + j];
            sbv[j] = sb[uco * 8 + j];
        }
#pragma unroll
        for (int s = 0; s < 2; ++s) {
            int row = lane + 64 * s;
            float4 h0 = *(const float4*)&h[(r0 + row) * HD + uco * 8];
            float4 h1 = *(const float4*)&h[(r0 + row) * HD + uco * 8 + 4];
            *(float4*)&hrow[s][0] = h0; *(float4*)&hrow[s][4] = h1;
#pragma unroll
            for (int i = 0; i < 8; ++i) {
                float hnv = hrow[s][i] * sav[i] + sbv[i];
                float t = 2.0f * y[s][i] + hnv * dv[i];
                float u2 = 1.5957691216057308f * (t + 0.044715f * t * t * t);
                gg[s][i] = t / (1.0f + __expf(-u2));
            }
        }
    }
    __syncthreads();   // C-proj buf + ct reads done
#pragma unroll
    for (int s = 0; s < 2; ++s) {
        int row = lane + 64 * s;
        *(float4*)&buf[row * BSTR + uco * 8]     = make_float4(gg[s][0], gg[s][1], gg[s][2], gg[s][3]);
        *(float4*)&buf[row * BSTR + uco * 8 + 4] = make_float4(gg[s][4], gg[s][5], gg[s][6], gg[s][7]);
    }
#pragma unroll
    for (int it = 0; it < 2; ++it) {
        int idx = it * 512 + tid;
        *(float4*)&wbuf[idx * 4]        = *(const float4*)&w1t[(size_t)l * 4096 + idx * 4];
        *(float4*)&wbuf[4096 + idx * 4] = *(const float4*)&w2t[(size_t)l * 4096 + idx * 4];
    }
    __syncthreads();

    // GLU
    float uacc[2][8], sacc[2][8];
    {
        float bb1[8], bb2[8];
        const float* b1p = &b1[l * HD + uco * 8];   // uniform
        const float* b2p = &b2[l * HD + uco * 8];   // uniform
#pragma unroll
        for (int j = 0; j < 8; ++j) { bb1[j] = b1p[j]; bb2[j] = b2p[j]; }
#pragma unroll
        for (int s = 0; s < 2; ++s)
#pragma unroll
            for (int j = 0; j < 8; ++j) { uacc[s][j] = bb1[j]; sacc[s][j] = bb2[j]; }
    }
    for (int k4 = 0; k4 < 16; ++k4) {
        float4 gk[2];
#pragma unroll
        for (int s = 0; s < 2; ++s)
            gk[s] = *(const float4*)&buf[(lane + 64 * s) * BSTR + k4 * 4];
#pragma unroll
        for (int kk = 0; kk < 4; ++kk) {
            float av[8], cv[8];
            const float* p1w = &wbuf[(k4 * 4 + kk) * 64 + uco * 8];          // uniform
            const float* p2w = &wbuf[4096 + (k4 * 4 + kk) * 64 + uco * 8];   // uniform
            *(float4*)&av[0] = *(const float4*)&p1w[0];
            *(float4*)&av[4] = *(const float4*)&p1w[4];
            *(float4*)&cv[0] = *(const float4*)&p2w[0];
            *(float4*)&cv[4] = *(const float4*)&p2w[4];
#pragma unroll
            for (int s = 0; s < 2; ++s) {
                float gv = compsel(gk[s], kk);
#pragma unroll
                for (int j = 0; j < 8; ++j) {
                    uacc[s][j] += gv * av[j];
                    sacc[s][j] += gv * cv[j];
                }
            }
        }
    }

    if (LAST) {
        float dw0[8], dw1[8];
#pragma unroll
        for (int j = 0; j < 8; ++j) {
            dw0[j] = dec_w[uco * 8 + j];
            dw1[j] = dec_w[64 + uco * 8 + j];
        }
        float db0 = dec_b[0], db1 = dec_b[1];
        __syncthreads();   // GLU wbuf reads done before reuse
#pragma unroll
        for (int s = 0; s < 2; ++s) {
            int row = lane + 64 * s;
            float o0 = 0.0f, o1 = 0.0f;
#pragma unroll
            for (int i = 0; i < 8; ++i) {
                float sg = 1.0f / (1.0f + __expf(-sacc[s][i]));
                float ho = hrow[s][i] + uacc[s][i] * sg;
                o0 += ho * dw0[i];
                o1 += ho * dw1[i];
            }
            wbuf[row * 16 + uco * 2]     = o0;
            wbuf[row * 16 + uco * 2 + 1] = o1;
        }
        __syncthreads();
        if (tid < 128) {
            float a0 = 0.0f, a1 = 0.0f;
#pragma unroll
            for (int w = 0; w < 8; ++w) {
                a0 += wbuf[tid * 16 + 2 * w];
                a1 += wbuf[tid * 16 + 2 * w + 1];
            }
            *(float2*)&outp[(r0 + tid) * 2] = make_float2(a0 + db0, a1 + db1);
        }
    } else {
        float ho[2][8];
#pragma unroll
        for (int s = 0; s < 2; ++s) {
            int row = lane + 64 * s;
#pragma unroll
            for (int i = 0; i < 8; ++i) {
                float sg = 1.0f / (1.0f + __expf(-sacc[s][i]));
                ho[s][i] = hrow[s][i] + uacc[s][i] * sg;
            }
            *(float4*)&hout[(r0 + row) * HD + uco * 8] =
                make_float4(ho[s][0], ho[s][1], ho[s][2], ho[s][3]);
            *(float4*)&hout[(r0 + row) * HD + uco * 8 + 4] =
                make_float4(ho[s][4], ho[s][5], ho[s][6], ho[s][7]);
        }
#pragma unroll
        for (int i = 0; i < 8; ++i) {
            float v1 = ho[0][i] + ho[1][i];
            float v2 = ho[0][i] * ho[0][i] + ho[1][i] * ho[1][i];
#pragma unroll
            for (int m = 1; m < 64; m <<= 1) { v1 += __shfl_xor(v1, m, 64); v2 += __shfl_xor(v2, m, 64); }
            if (lane == 0) { sp1[wid * 8 + i] = v1; sp2[wid * 8 + i] = v2; }
        }
        __syncthreads();
        if (tid < 64) {
            atomicAdd(&stats_next[tid],      sp1[tid]);
            atomicAdd(&stats_next[64 + tid], sp2[tid]);
        }
    }
}

// ---------------------------------------------------------------- launch
extern "C" void kernel_launch(void* const* d_in, const int* in_sizes, int n_in,
                              void* d_out, int out_size, void* d_ws, size_t ws_size,
                              hipStream_t stream)
{
    (void)in_sizes; (void)n_in; (void)out_size; (void)ws_size;
    const float* x     = (const float*)d_in[0];
    const int*   gidx  = (const int*)d_in[1];
    const float* enc_w = (const float*)d_in[2];
    const float* enc_b = (const float*)d_in[3];
    const float* ctx   = (const float*)d_in[4];
    const float* Lre   = (const float*)d_in[5];
    const float* Lim   = (const float*)d_in[6];
    const float* Bre   = (const float*)d_in[7];
    const float* Bim   = (const float*)d_in[8];
    const float* Cre   = (const float*)d_in[9];
    const float* Cim   = (const float*)d_in[10];
    const float* Dv    = (const float*)d_in[11];
    const float* lstep = (const float*)d_in[12];
    const float* nsc   = (const float*)d_in[13];
    const float* nbi   = (const float*)d_in[14];
    const float* w1    = (const float*)d_in[15];
    const float* b1    = (const float*)d_in[16];
    const float* w2    = (const float*)d_in[17];
    const float* b2    = (const float*)d_in[18];
    const float* dw    = (const float*)d_in[19];
    const float* db    = (const float*)d_in[20];
    float* out = (float*)d_out;

    float* ws = (float*)d_ws;
    float* h      = ws;  ws += (size_t)T_LEN * HD;
    float* xs     = ws;  ws += (size_t)T_LEN * HD;
    float* carry  = ws;  ws += (size_t)NBLK * HD;
    float* pc     = ws;  ws += (size_t)NBLK * HD;
    float* stats  = ws;  ws += NLAY * 128;
    float* Lbar   = ws;  ws += NLAY * PD * 2;
    float* Ldt    = ws;  ws += NLAY * PD * 2;
    float* Bbar_t = ws;  ws += NLAY * HD * HD;
    float* Ct     = ws;  ws += NLAY * PD * 128;
    float* w1t    = ws;  ws += NLAY * HD * HD;
    float* w2t    = ws;  ws += NLAY * HD * HD;
    float* wenc   = ws;  ws += IN_DIM * HD;

    ssm_k0_setup<<<1, 512, 0, stream>>>(Lre, Lim, lstep, Bre, Bim, Cre, Cim, w1, w2,
                                        enc_w, gidx, Lbar, Ldt, Bbar_t, Ct, w1t, w2t,
                                        wenc, stats);
    ssm_k1_encoder<<<512, 256, 0, stream>>>(x, gidx, wenc, enc_b, ctx, h, stats);
    for (int l = 0; l < NLAY; ++l) {
        ssm_k2_bu_scan<<<NBLK, 512, 0, stream>>>(h, stats, nsc, nbi, Bbar_t, Lbar, xs, carry, l);
        ssm_k3_carry<<<PD, 64, 0, stream>>>(carry, Ldt, pc, l);
        if (l < NLAY - 1) {
            ssm_k4_out<false><<<NBLK, 512, 0, stream>>>(
                h, xs, pc, stats, nsc, nbi, Ldt, Ct, Dv, w1t, b1, w2t, b2,
                h, stats + (l + 1) * 128, dw, db, out, l);
        } else {
            ssm_k4_out<true><<<NBLK, 512, 0, stream>>>(
                h, xs, pc, stats, nsc, nbi, Ldt, Ct, Dv, w1t, b1, w2t, b2,
                h, stats, dw, db, out, l);
        }
    }
}

// Round 8
// 339.837 us; speedup vs baseline: 4.1561x; 1.6108x over previous
//
#include <hip/hip_runtime.h>

#define T_LEN   131072
#define IN_DIM  256
#define HD      64
#define PD      32
#define NLAY    4
#define CHUNK   128
#define NBLK    (T_LEN / CHUNK)   // 1024
#define ASTR    68                // act stride (u32): 68 % 32 == 4 -> conflict-free b128 column reads

typedef __attribute__((ext_vector_type(8))) short bf16x8;
typedef __attribute__((ext_vector_type(4))) float f32x4;

union FragU { uint4 q; bf16x8 v; };

// split fp32 -> two bf16 (hi in low16, lo in high16)
__device__ __forceinline__ unsigned splitpack(float x) {
    unsigned xb = __float_as_uint(x);
    unsigned hb = (xb + 0x8000u) & 0xffff0000u;
    float lf = x - __uint_as_float(hb);
    unsigned lb = (__float_as_uint(lf) + 0x8000u) >> 16;
    return (hb >> 16) | (lb << 16);
}

__device__ __forceinline__ void unpackA(uint4 a0, uint4 a1, bf16x8& hi, bf16x8& lo) {
    union { bf16x8 v; unsigned u[4]; } H, L;
    H.u[0] = (a0.x & 0xffffu) | (a0.y << 16);
    H.u[1] = (a0.z & 0xffffu) | (a0.w << 16);
    H.u[2] = (a1.x & 0xffffu) | (a1.y << 16);
    H.u[3] = (a1.z & 0xffffu) | (a1.w << 16);
    L.u[0] = (a0.x >> 16) | (a0.y & 0xffff0000u);
    L.u[1] = (a0.z >> 16) | (a0.w & 0xffff0000u);
    L.u[2] = (a1.x >> 16) | (a1.y & 0xffff0000u);
    L.u[3] = (a1.z >> 16) | (a1.w & 0xffff0000u);
    hi = H.v; lo = L.v;
}

#define MFMA3(ACC, AH, AL, BH, BL)                                              \
    ACC = __builtin_amdgcn_mfma_f32_16x16x32_bf16(AH, BH, ACC, 0, 0, 0);        \
    ACC = __builtin_amdgcn_mfma_f32_16x16x32_bf16(AH, BL, ACC, 0, 0, 0);        \
    ACC = __builtin_amdgcn_mfma_f32_16x16x32_bf16(AL, BH, ACC, 0, 0, 0);

// assumed k mapping (consistent for A and B -> correctness independent of HW choice)
__device__ __forceinline__ int kmap(int q, int j) {
    return (j < 4) ? (q * 4 + j) : (16 + q * 4 + (j - 4));
}

// ---------------------------------------------------------------- K0a: small setup
__global__ __launch_bounds__(512) void ssm_k0a(
    const float* __restrict__ Lre, const float* __restrict__ Lim,
    const float* __restrict__ logstep,
    float* __restrict__ Lbar, float* __restrict__ Ldt, float* __restrict__ stats)
{
    int tid = threadIdx.x;
    if (tid < NLAY * PD) {
        int l = tid >> 5, p = tid & 31;
        float dt = expf(logstep[l * PD + p]);
        float lr = Lre[l * PD + p], li = Lim[l * PD + p];
        float ldr = lr * dt, ldi = li * dt;
        Ldt[tid * 2] = ldr; Ldt[tid * 2 + 1] = ldi;
        float e = expf(ldr);
        float sn, cs; sincosf(ldi, &sn, &cs);
        Lbar[tid * 2] = e * cs; Lbar[tid * 2 + 1] = e * sn;
    }
    if (tid < NLAY * 128) stats[tid] = 0.0f;
}

// ---------------------------------------------------------------- K0b: weight fragment builder
// mat 0 = encoder [256k][64n]; per layer: 1=Bbar^T, 2=C(real-ified), 3=w1^T, 4=w2^T (all [64][64]).
__global__ __launch_bounds__(256) void ssm_k0b(
    const float* __restrict__ Lre, const float* __restrict__ Lim,
    const float* __restrict__ logstep,
    const float* __restrict__ Bre, const float* __restrict__ Bim,
    const float* __restrict__ Cre, const float* __restrict__ Cim,
    const float* __restrict__ w1, const float* __restrict__ w2,
    const float* __restrict__ enc_w, const int* __restrict__ gptr,
    unsigned* __restrict__ fragE, unsigned* __restrict__ fragL)
{
    int fi = blockIdx.x * 256 + threadIdx.x;   // 0..10239
    if (fi >= 10240) return;
    int g = gptr[0];
    int mat, lay = 0, rem;
    unsigned* outp;
    if (fi < 2048) { mat = 0; rem = fi; outp = fragE + rem * 8; }
    else {
        int t = fi - 2048;
        lay = t / 2048;
        int r2 = t % 2048;
        mat = 1 + r2 / 512;
        rem = r2 % 512;
        outp = fragL + ((size_t)(lay * 4 + (mat - 1)) * 512 + rem) * 8;
    }
    int ks = (mat == 0) ? (rem / 256) : (rem / 256);
    int nt = (rem / 64) & 3;
    int lane = rem & 63;
    int q = lane >> 4;
    int n = nt * 16 + (lane & 15);

    float vals[8];
#pragma unroll
    for (int j = 0; j < 8; ++j) {
        int k = ks * 32 + kmap(q, j);
        float v;
        if (mat == 0) {
            v = (n < 56) ? enc_w[(size_t)(g * 56 + n) * IN_DIM + k] : 0.0f;
        } else if (mat == 1) {
            int p = n >> 1;
            float dt = expf(logstep[lay * PD + p]);
            float lr = Lre[lay * PD + p], li = Lim[lay * PD + p];
            float e = expf(lr * dt);
            float sn, cs; sincosf(li * dt, &sn, &cs);
            float den = lr * lr + li * li;
            float nr = e * cs - 1.0f, ni = e * sn;
            float fr = (nr * lr + ni * li) / den, fimag = (ni * lr - nr * li) / den;
            float br = Bre[(lay * PD + p) * HD + k], bi = Bim[(lay * PD + p) * HD + k];
            v = (n & 1) ? (fr * bi + fimag * br) : (fr * br - fimag * bi);
        } else if (mat == 2) {
            int p = k >> 1;
            v = (k & 1) ? -Cim[((size_t)lay * HD + n) * PD + p]
                        :  Cre[((size_t)lay * HD + n) * PD + p];
        } else if (mat == 3) {
            v = w1[((size_t)lay * HD + n) * HD + k];
        } else {
            v = w2[((size_t)lay * HD + n) * HD + k];
        }
        vals[j] = v;
    }
    unsigned p8[8];
#pragma unroll
    for (int j = 0; j < 8; ++j) p8[j] = splitpack(vals[j]);
#pragma unroll
    for (int w = 0; w < 4; ++w) {
        unsigned p0 = p8[2 * w], p1 = p8[2 * w + 1];
        outp[w]     = (p0 & 0xffffu) | (p1 << 16);          // hi pair
        outp[4 + w] = (p0 >> 16) | (p1 & 0xffff0000u);      // lo pair
    }
}

// ---------------------------------------------------------------- K1: encoder (MFMA)
// 1024 blocks x 512 thr (8 waves). wave w owns rows 16w..16w+15 of its 128-row chunk.
__global__ __launch_bounds__(512, 4) void ssm_k1_encoder(
    const float* __restrict__ x, const int* __restrict__ gptr,
    const unsigned* __restrict__ fragE, const float* __restrict__ enc_b,
    const float* __restrict__ ctx_emb,
    float* __restrict__ h, float* __restrict__ stats)
{
    __shared__ __attribute__((aligned(16))) unsigned act[128 * ASTR];
    __shared__ float sp1[512], sp2[512];
    int tid = threadIdx.x;
    int l = tid & 63, w = tid >> 6;
    int cq = l >> 4, cr = l & 15;
    int g = gptr[0];
    size_t r0 = (size_t)blockIdx.x * 128;
    int arow = 16 * w + cr;
    const f32x4 fzero = {0.f, 0.f, 0.f, 0.f};

    f32x4 acc[4];
#pragma unroll
    for (int nt = 0; nt < 4; ++nt) acc[nt] = fzero;

    for (int kt = 0; kt < 4; ++kt) {
        asm volatile("s_waitcnt lgkmcnt(0)" ::: "memory");   // prev reads drained
        // wave-local stage: row arow, 16 cols (cq quarter), split-packed
#pragma unroll
        for (int j = 0; j < 4; ++j) {
            float4 xv = *(const float4*)&x[(r0 + arow) * IN_DIM + kt * 64 + cq * 16 + j * 4];
            uint4 u;
            u.x = splitpack(xv.x); u.y = splitpack(xv.y);
            u.z = splitpack(xv.z); u.w = splitpack(xv.w);
            *(uint4*)&act[arow * ASTR + cq * 16 + j * 4] = u;
        }
        asm volatile("s_waitcnt lgkmcnt(0)" ::: "memory");   // writes visible to wave
        bf16x8 ah[2], al[2];
#pragma unroll
        for (int ks = 0; ks < 2; ++ks) {
            int col = ks * 32 + 4 * cq;
            uint4 a0 = *(const uint4*)&act[arow * ASTR + col];
            uint4 a1 = *(const uint4*)&act[arow * ASTR + col + 16];
            unpackA(a0, a1, ah[ks], al[ks]);
        }
#pragma unroll
        for (int ks = 0; ks < 2; ++ks) {
            int ksg = kt * 2 + ks;
#pragma unroll
            for (int nt = 0; nt < 4; ++nt) {
                const uint4* wf = (const uint4*)&fragE[((size_t)(ksg * 4 + nt) * 64 + l) * 8];
                FragU BH, BL; BH.q = wf[0]; BL.q = wf[1];
                MFMA3(acc[nt], ah[ks], al[ks], BH.v, BL.v);
            }
        }
    }
    // epilogue: bias/ctx, store h, stats
#pragma unroll
    for (int nt = 0; nt < 4; ++nt) {
        int ch = nt * 16 + cr;
        float eb = (ch < 56) ? enc_b[g * 56 + ch] : 0.0f;
        bool isctx = (ch >= 56);
        float cv = isctx ? ctx_emb[g * 8 + (ch - 56)] : 0.0f;
        float v1 = 0.0f, v2 = 0.0f;
#pragma unroll
        for (int r = 0; r < 4; ++r) {
            float val = isctx ? cv : (acc[nt][r] + eb);
            h[(r0 + 16 * w + 4 * cq + r) * HD + ch] = val;
            v1 += val; v2 += val * val;
        }
        v1 += __shfl_xor(v1, 16, 64); v2 += __shfl_xor(v2, 16, 64);
        v1 += __shfl_xor(v1, 32, 64); v2 += __shfl_xor(v2, 32, 64);
        if (l < 16) { sp1[w * 64 + ch] = v1; sp2[w * 64 + ch] = v2; }
    }
    __syncthreads();
    if (tid < 64) {
        float s1 = 0.0f, s2 = 0.0f;
#pragma unroll
        for (int ww = 0; ww < 8; ++ww) { s1 += sp1[ww * 64 + tid]; s2 += sp2[ww * 64 + tid]; }
        atomicAdd(&stats[tid], s1);
        atomicAdd(&stats[64 + tid], s2);
    }
}

// ---------------------------------------------------------------- K2: hn -> Bu (MFMA) -> local scan
__global__ __launch_bounds__(512, 4) void ssm_k2_bu_scan(
    const float* __restrict__ h, const float* __restrict__ stats,
    const float* __restrict__ nscale, const float* __restrict__ nbias,
    const unsigned* __restrict__ fragL, const float* __restrict__ Lbar,
    float* __restrict__ xs, float* __restrict__ carry, int lay)
{
    __shared__ __attribute__((aligned(16))) unsigned act[128 * ASTR];
    __shared__ float lsa[HD], lsb[HD];
    int tid = threadIdx.x;
    int l = tid & 63, w = tid >> 6;
    int cq = l >> 4, cr = l & 15;
    size_t r0 = (size_t)blockIdx.x * CHUNK;
    int arow = 16 * w + cr;
    float* bf = (float*)act;
    const f32x4 fzero = {0.f, 0.f, 0.f, 0.f};

    if (tid < HD) {
        float s1 = stats[lay * 128 + tid], s2 = stats[lay * 128 + 64 + tid];
        float mu = s1 * (1.0f / T_LEN);
        float var = fmaxf(s2 * (1.0f / T_LEN) - mu * mu, 0.0f);
        float sc = nscale[lay * HD + tid] * rsqrtf(var + 1e-5f);
        lsa[tid] = sc;
        lsb[tid] = nbias[lay * HD + tid] - mu * sc;
    }
    __syncthreads();

    // wave-local stage: hn split-packed
#pragma unroll
    for (int j = 0; j < 4; ++j) {
        int c0 = cq * 16 + j * 4;
        float4 hv = *(const float4*)&h[(r0 + arow) * HD + c0];
        uint4 u;
        u.x = splitpack(hv.x * lsa[c0]     + lsb[c0]);
        u.y = splitpack(hv.y * lsa[c0 + 1] + lsb[c0 + 1]);
        u.z = splitpack(hv.z * lsa[c0 + 2] + lsb[c0 + 2]);
        u.w = splitpack(hv.w * lsa[c0 + 3] + lsb[c0 + 3]);
        *(uint4*)&act[arow * ASTR + c0] = u;
    }
    asm volatile("s_waitcnt lgkmcnt(0)" ::: "memory");

    // Bu GEMM
    const unsigned* fB = fragL + (size_t)(lay * 4 + 0) * 4096;
    bf16x8 ah[2], al[2];
#pragma unroll
    for (int ks = 0; ks < 2; ++ks) {
        int col = ks * 32 + 4 * cq;
        uint4 a0 = *(const uint4*)&act[arow * ASTR + col];
        uint4 a1 = *(const uint4*)&act[arow * ASTR + col + 16];
        unpackA(a0, a1, ah[ks], al[ks]);
    }
    f32x4 acc[4];
#pragma unroll
    for (int nt = 0; nt < 4; ++nt) acc[nt] = fzero;
#pragma unroll
    for (int ks = 0; ks < 2; ++ks)
#pragma unroll
        for (int nt = 0; nt < 4; ++nt) {
            const uint4* wf = (const uint4*)&fB[((size_t)(ks * 4 + nt) * 64 + l) * 8];
            FragU BH, BL; BH.q = wf[0]; BL.q = wf[1];
            MFMA3(acc[nt], ah[ks], al[ks], BH.v, BL.v);
        }
    // Bu -> act (fp32), own rows (data-dependent on reads: safe)
#pragma unroll
    for (int nt = 0; nt < 4; ++nt)
#pragma unroll
        for (int r = 0; r < 4; ++r)
            bf[(16 * w + 4 * cq + r) * ASTR + nt * 16 + cr] = acc[nt][r];
    __syncthreads();

    // in-chunk scan: wave 0, slot = 2p+ri
    if (tid < 64) {
        int p = l >> 1;
        float Lr = Lbar[(lay * PD + p) * 2];
        float Lj = Lbar[(lay * PD + p) * 2 + 1];
        float csn = (l & 1) ? Lj : -Lj;
        float xv = 0.0f;
        for (int t = 0; t < CHUNK; ++t) {
            float b = bf[t * ASTR + l];
            float xo = __shfl_xor(xv, 1, 64);
            xv = Lr * xv + csn * xo + b;
            bf[t * ASTR + l] = xv;
        }
        carry[(size_t)blockIdx.x * 64 + l] = xv;
    }
    __syncthreads();
    // xs store (wave-local rows)
#pragma unroll
    for (int j = 0; j < 4; ++j) {
        float4 v = *(float4*)&bf[arow * ASTR + cq * 16 + j * 4];
        *(float4*)&xs[(r0 + arow) * HD + cq * 16 + j * 4] = v;
    }
}

// ---------------------------------------------------------------- K3: cross-chunk carry scan (unchanged)
__global__ __launch_bounds__(64) void ssm_k3_carry(
    const float* __restrict__ carry, const float* __restrict__ Ldt,
    float* __restrict__ pc, int lay)
{
    int p = blockIdx.x;
    int lane = threadIdx.x;
    float ldr = Ldt[(lay * PD + p) * 2], ldi = Ldt[(lay * PD + p) * 2 + 1];
    float er = __expf(ldr * (float)CHUNK);
    float an = ldi * (float)CHUNK;
    float lcr = er * __cosf(an), lci = er * __sinf(an);
    float cr[16], ci[16];
#pragma unroll
    for (int j = 0; j < 16; ++j) {
        cr[j] = carry[(size_t)(lane * 16 + j) * 64 + 2 * p];
        ci[j] = carry[(size_t)(lane * 16 + j) * 64 + 2 * p + 1];
    }
    float ur = 0.0f, ui = 0.0f;
#pragma unroll
    for (int j = 0; j < 16; ++j) {
        float nr = lcr * ur - lci * ui + cr[j];
        float ni = lcr * ui + lci * ur + ci[j];
        ur = nr; ui = ni;
    }
    float mr = lcr, mi = lci;
#pragma unroll
    for (int s = 0; s < 4; ++s) { float t = mr * mr - mi * mi; mi = 2.0f * mr * mi; mr = t; }
#pragma unroll
    for (int d = 1; d < 64; d <<= 1) {
        float tr = __shfl_up(ur, d, 64);
        float ti = __shfl_up(ui, d, 64);
        if (lane >= d) { ur = mr * tr - mi * ti + ur; ui = mr * ti + mi * tr + ui; }
        float t = mr * mr - mi * mi; mi = 2.0f * mr * mi; mr = t;
    }
    float pr = __shfl_up(ur, 1, 64), pi = __shfl_up(ui, 1, 64);
    float xr = (lane == 0) ? 0.0f : pr;
    float xi = (lane == 0) ? 0.0f : pi;
#pragma unroll
    for (int j = 0; j < 16; ++j) {
        pc[(size_t)(lane * 16 + j) * 64 + 2 * p]     = xr;
        pc[(size_t)(lane * 16 + j) * 64 + 2 * p + 1] = xi;
        float nr = lcr * xr - lci * xi + cr[j];
        float ni = lcr * xi + lci * xr + ci[j];
        xr = nr; xi = ni;
    }
}

// ---------------------------------------------------------------- K4: fixup + C-proj + gelu + GLU + residual (MFMA)
template <bool LAST>
__global__ __launch_bounds__(512, 4) void ssm_k4_out(
    const float* __restrict__ h, const float* __restrict__ xs,
    const float* __restrict__ pc, const float* __restrict__ stats,
    const float* __restrict__ nscale, const float* __restrict__ nbias,
    const float* __restrict__ Ldt, const unsigned* __restrict__ fragL,
    const float* __restrict__ Dv,
    const float* __restrict__ b1, const float* __restrict__ b2,
    float* __restrict__ hout, float* __restrict__ stats_next,
    const float* __restrict__ dec_w, const float* __restrict__ dec_b,
    float* __restrict__ outp, int lay)
{
    __shared__ __attribute__((aligned(16))) unsigned act[128 * ASTR];
    __shared__ float lsa[HD], lsb[HD], lsd[HD];
    __shared__ float sp1[512], sp2[512];
    int tid = threadIdx.x;
    int l = tid & 63, w = tid >> 6;
    int cq = l >> 4, cr = l & 15;
    size_t r0 = (size_t)blockIdx.x * CHUNK;
    int arow = 16 * w + cr;
    const f32x4 fzero = {0.f, 0.f, 0.f, 0.f};

    if (tid < HD) {
        float s1 = stats[lay * 128 + tid], s2 = stats[lay * 128 + 64 + tid];
        float mu = s1 * (1.0f / T_LEN);
        float var = fmaxf(s2 * (1.0f / T_LEN) - mu * mu, 0.0f);
        float sc = nscale[lay * HD + tid] * rsqrtf(var + 1e-5f);
        lsa[tid] = sc;
        lsb[tid] = nbias[lay * HD + tid] - mu * sc;
        lsd[tid] = Dv[lay * HD + tid];
    }
    // phase 1: wave-local xs stage + carry fixup -> split-packed act
    {
        int cb = cq * 16;
        float xf[16], pcv[16], ldv[16];
#pragma unroll
        for (int j = 0; j < 4; ++j)
            *(float4*)&xf[j * 4] = *(const float4*)&xs[(r0 + arow) * HD + cb + j * 4];
#pragma unroll
        for (int e = 0; e < 16; ++e) {
            pcv[e] = pc[(size_t)blockIdx.x * 64 + cb + e];
            ldv[e] = Ldt[lay * 64 + cb + e];
        }
        float tt = (float)(arow + 1);
#pragma unroll
        for (int pp = 0; pp < 8; ++pp) {
            float e1 = __expf(ldv[2 * pp] * tt);
            float an = ldv[2 * pp + 1] * tt;
            float prr = e1 * __cosf(an), pri = e1 * __sinf(an);
            xf[2 * pp]     += prr * pcv[2 * pp]     - pri * pcv[2 * pp + 1];
            xf[2 * pp + 1] += prr * pcv[2 * pp + 1] + pri * pcv[2 * pp];
        }
#pragma unroll
        for (int j = 0; j < 4; ++j) {
            uint4 u;
            u.x = splitpack(xf[j * 4]);     u.y = splitpack(xf[j * 4 + 1]);
            u.z = splitpack(xf[j * 4 + 2]); u.w = splitpack(xf[j * 4 + 3]);
            *(uint4*)&act[arow * ASTR + cb + j * 4] = u;
        }
    }
    __syncthreads();

    // phase 2: C projection GEMM -> y
    const unsigned* fC = fragL + (size_t)(lay * 4 + 1) * 4096;
    f32x4 yacc[4];
#pragma unroll
    for (int nt = 0; nt < 4; ++nt) yacc[nt] = fzero;
    {
        bf16x8 ah[2], al[2];
#pragma unroll
        for (int ks = 0; ks < 2; ++ks) {
            int col = ks * 32 + 4 * cq;
            uint4 a0 = *(const uint4*)&act[arow * ASTR + col];
            uint4 a1 = *(const uint4*)&act[arow * ASTR + col + 16];
            unpackA(a0, a1, ah[ks], al[ks]);
        }
#pragma unroll
        for (int ks = 0; ks < 2; ++ks)
#pragma unroll
            for (int nt = 0; nt < 4; ++nt) {
                const uint4* wf = (const uint4*)&fC[((size_t)(ks * 4 + nt) * 64 + l) * 8];
                FragU BH, BL; BH.q = wf[0]; BL.q = wf[1];
                MFMA3(yacc[nt], ah[ks], al[ks], BH.v, BL.v);
            }
    }

    // phase 3: h load (D positions), gelu(2y + hn*D) -> g split-packed into act
    float hrow[16];
#pragma unroll
    for (int nt = 0; nt < 4; ++nt) {
        int ch = nt * 16 + cr;
        float sav = lsa[ch], sbv = lsb[ch], dvv = lsd[ch];
#pragma unroll
        for (int r = 0; r < 4; ++r) {
            int row = 16 * w + 4 * cq + r;
            float hv = h[(r0 + row) * HD + ch];
            hrow[nt * 4 + r] = hv;
            float t = 2.0f * yacc[nt][r] + (hv * sav + sbv) * dvv;
            float u2 = 1.5957691216057308f * (t + 0.044715f * t * t * t);
            float gv = t / (1.0f + __expf(-u2));
            act[row * ASTR + ch] = splitpack(gv);
        }
    }
    asm volatile("s_waitcnt lgkmcnt(0)" ::: "memory");

    // phase 4: GLU 2 GEMMs (shared A-frags)
    const unsigned* f1 = fragL + (size_t)(lay * 4 + 2) * 4096;
    const unsigned* f2 = fragL + (size_t)(lay * 4 + 3) * 4096;
    f32x4 uacc[4], sacc[4];
#pragma unroll
    for (int nt = 0; nt < 4; ++nt) { uacc[nt] = fzero; sacc[nt] = fzero; }
    {
        bf16x8 ah[2], al[2];
#pragma unroll
        for (int ks = 0; ks < 2; ++ks) {
            int col = ks * 32 + 4 * cq;
            uint4 a0 = *(const uint4*)&act[arow * ASTR + col];
            uint4 a1 = *(const uint4*)&act[arow * ASTR + col + 16];
            unpackA(a0, a1, ah[ks], al[ks]);
        }
#pragma unroll
        for (int ks = 0; ks < 2; ++ks)
#pragma unroll
            for (int nt = 0; nt < 4; ++nt) {
                const uint4* w1f = (const uint4*)&f1[((size_t)(ks * 4 + nt) * 64 + l) * 8];
                FragU BH1, BL1; BH1.q = w1f[0]; BL1.q = w1f[1];
                MFMA3(uacc[nt], ah[ks], al[ks], BH1.v, BL1.v);
                const uint4* w2f = (const uint4*)&f2[((size_t)(ks * 4 + nt) * 64 + l) * 8];
                FragU BH2, BL2; BH2.q = w2f[0]; BL2.q = w2f[1];
                MFMA3(sacc[nt], ah[ks], al[ks], BH2.v, BL2.v);
            }
    }

    // phase 5
    if (LAST) {
        float o0[4] = {0.f, 0.f, 0.f, 0.f}, o1[4] = {0.f, 0.f, 0.f, 0.f};
#pragma unroll
        for (int nt = 0; nt < 4; ++nt) {
            int ch = nt * 16 + cr;
            float bb1 = b1[lay * HD + ch], bb2 = b2[lay * HD + ch];
            float dw0 = dec_w[ch], dw1 = dec_w[64 + ch];
#pragma unroll
            for (int r = 0; r < 4; ++r) {
                float sv = sacc[nt][r] + bb2;
                float sg = 1.0f / (1.0f + __expf(-sv));
                float ho = hrow[nt * 4 + r] + (uacc[nt][r] + bb1) * sg;
                o0[r] += ho * dw0;
                o1[r] += ho * dw1;
            }
        }
#pragma unroll
        for (int r = 0; r < 4; ++r) {
#pragma unroll
            for (int m = 1; m < 16; m <<= 1) {
                o0[r] += __shfl_xor(o0[r], m, 64);
                o1[r] += __shfl_xor(o1[r], m, 64);
            }
        }
        if (cr == 0) {
            float db0 = dec_b[0], db1 = dec_b[1];
#pragma unroll
            for (int r = 0; r < 4; ++r) {
                int row = 16 * w + 4 * cq + r;
                *(float2*)&outp[(r0 + row) * 2] = make_float2(o0[r] + db0, o1[r] + db1);
            }
        }
    } else {
#pragma unroll
        for (int nt = 0; nt < 4; ++nt) {
            int ch = nt * 16 + cr;
            float bb1 = b1[lay * HD + ch], bb2 = b2[lay * HD + ch];
            float v1 = 0.0f, v2 = 0.0f;
#pragma unroll
            for (int r = 0; r < 4; ++r) {
                int row = 16 * w + 4 * cq + r;
                float sv = sacc[nt][r] + bb2;
                float sg = 1.0f / (1.0f + __expf(-sv));
                float ho = hrow[nt * 4 + r] + (uacc[nt][r] + bb1) * sg;
                hout[(r0 + row) * HD + ch] = ho;
                v1 += ho; v2 += ho * ho;
            }
            v1 += __shfl_xor(v1, 16, 64); v2 += __shfl_xor(v2, 16, 64);
            v1 += __shfl_xor(v1, 32, 64); v2 += __shfl_xor(v2, 32, 64);
            if (l < 16) { sp1[w * 64 + ch] = v1; sp2[w * 64 + ch] = v2; }
        }
        __syncthreads();
        if (tid < 64) {
            float s1 = 0.0f, s2 = 0.0f;
#pragma unroll
            for (int ww = 0; ww < 8; ++ww) { s1 += sp1[ww * 64 + tid]; s2 += sp2[ww * 64 + tid]; }
            atomicAdd(&stats_next[tid], s1);
            atomicAdd(&stats_next[64 + tid], s2);
        }
    }
}

// ---------------------------------------------------------------- launch
extern "C" void kernel_launch(void* const* d_in, const int* in_sizes, int n_in,
                              void* d_out, int out_size, void* d_ws, size_t ws_size,
                              hipStream_t stream)
{
    (void)in_sizes; (void)n_in; (void)out_size; (void)ws_size;
    const float* x     = (const float*)d_in[0];
    const int*   gidx  = (const int*)d_in[1];
    const float* enc_w = (const float*)d_in[2];
    const float* enc_b = (const float*)d_in[3];
    const float* ctx   = (const float*)d_in[4];
    const float* Lre   = (const float*)d_in[5];
    const float* Lim   = (const float*)d_in[6];
    const float* Bre   = (const float*)d_in[7];
    const float* Bim   = (const float*)d_in[8];
    const float* Cre   = (const float*)d_in[9];
    const float* Cim   = (const float*)d_in[10];
    const float* Dv    = (const float*)d_in[11];
    const float* lstep = (const float*)d_in[12];
    const float* nsc   = (const float*)d_in[13];
    const float* nbi   = (const float*)d_in[14];
    const float* w1    = (const float*)d_in[15];
    const float* b1    = (const float*)d_in[16];
    const float* w2    = (const float*)d_in[17];
    const float* b2    = (const float*)d_in[18];
    const float* dw    = (const float*)d_in[19];
    const float* db    = (const float*)d_in[20];
    float* out = (float*)d_out;

    float* ws = (float*)d_ws;
    float* h     = ws;  ws += (size_t)T_LEN * HD;
    float* xs    = ws;  ws += (size_t)T_LEN * HD;
    float* carry = ws;  ws += (size_t)NBLK * HD;
    float* pc    = ws;  ws += (size_t)NBLK * HD;
    float* stats = ws;  ws += NLAY * 128;
    float* Lbar  = ws;  ws += NLAY * PD * 2;
    float* Ldt   = ws;  ws += NLAY * PD * 2;
    unsigned* fragE = (unsigned*)ws;  ws += 16384;
    unsigned* fragL = (unsigned*)ws;  ws += 65536;

    ssm_k0a<<<1, 512, 0, stream>>>(Lre, Lim, lstep, Lbar, Ldt, stats);
    ssm_k0b<<<40, 256, 0, stream>>>(Lre, Lim, lstep, Bre, Bim, Cre, Cim, w1, w2,
                                    enc_w, gidx, fragE, fragL);
    ssm_k1_encoder<<<1024, 512, 0, stream>>>(x, gidx, fragE, enc_b, ctx, h, stats);
    for (int l = 0; l < NLAY; ++l) {
        ssm_k2_bu_scan<<<NBLK, 512, 0, stream>>>(h, stats, nsc, nbi, fragL, Lbar, xs, carry, l);
        ssm_k3_carry<<<PD, 64, 0, stream>>>(carry, Ldt, pc, l);
        if (l < NLAY - 1) {
            ssm_k4_out<false><<<NBLK, 512, 0, stream>>>(
                h, xs, pc, stats, nsc, nbi, Ldt, fragL, Dv, b1, b2,
                h, stats + (l + 1) * 128, dw, db, out, l);
        } else {
            ssm_k4_out<true><<<NBLK, 512, 0, stream>>>(
                h, xs, pc, stats, nsc, nbi, Ldt, fragL, Dv, b1, b2,
                h, stats, dw, db, out, l);
        }
    }
}